// Round 15
// baseline (213.120 us; speedup 1.0000x reference)
//
#include <hip/hip_runtime.h>
#include <math.h>

// Problem constants
#define BB 2
#define HH 64
#define WW 64
#define DM 192
#define DI 384
#define NS 16
#define DTR 12
#define LL 4096
#define ROWS (BB*LL)   // 8192
#define NCHUNK 128
#define LCHUNK 32      // NCHUNK*LCHUNK == LL
#define NCOMB 448      // padded combined-weight rows (416 real)
#define CSTRIDE ((size_t)BB * DI * 8)   // float2 elems per chunk slab
#define SAROW 72       // LDS row stride (bf16 elems) for BK=64 GEMM tiles

typedef __attribute__((ext_vector_type(8))) short bf16x8;
typedef __attribute__((ext_vector_type(4))) float f32x4;

__device__ __forceinline__ float silu_f(float v) {
    return v / (1.0f + __expf(-v));
}

// fp32 -> bf16 (RNE) bit trick
__device__ __forceinline__ unsigned short f2bf(float f) {
    union { float f; unsigned int u; } c; c.f = f;
    unsigned int u = c.u;
    u += 0x7fffu + ((u >> 16) & 1u);
    return (unsigned short)(u >> 16);
}
__device__ __forceinline__ float bf2f(unsigned short h) {
    union { unsigned int u; float f; } c; c.u = ((unsigned int)h) << 16;
    return c.f;
}

__device__ __forceinline__ bf16x8 f2bf8(float4 a, float4 b) {
    bf16x8 r;
    r[0] = (short)f2bf(a.x); r[1] = (short)f2bf(a.y);
    r[2] = (short)f2bf(a.z); r[3] = (short)f2bf(a.w);
    r[4] = (short)f2bf(b.x); r[5] = (short)f2bf(b.y);
    r[6] = (short)f2bf(b.z); r[7] = (short)f2bf(b.w);
    return r;
}

// ---------------------------------------------------------------------------
// One prep kernel: cast W_in/W_con/W_out to bf16 AND build combined weight
// Wc[448][384] (rows 0..383 = dt_w @ x_proj_w[:12], 384..415 = B/C rows).
// ---------------------------------------------------------------------------
__global__ __launch_bounds__(256) void prep_weights(
    const float* __restrict__ w_in, const float* __restrict__ w_con,
    const float* __restrict__ w_out,
    const float* __restrict__ x_proj_w, const float* __restrict__ dt_w,
    unsigned short* __restrict__ w_in_bf, unsigned short* __restrict__ w_con_bf,
    unsigned short* __restrict__ w_out_bf, unsigned short* __restrict__ wc)
{
    int idx = blockIdx.x * 256 + threadIdx.x;
    if (idx < 73728) {
        const float4* src; ushort4* dst; int off;
        if (idx < 36864)      { src = (const float4*)w_in;  dst = (ushort4*)w_in_bf;  off = idx; }
        else if (idx < 55296) { src = (const float4*)w_con; dst = (ushort4*)w_con_bf; off = idx - 36864; }
        else                  { src = (const float4*)w_out; dst = (ushort4*)w_out_bf; off = idx - 55296; }
        float4 v = src[off];
        ushort4 o;
        o.x = f2bf(v.x); o.y = f2bf(v.y); o.z = f2bf(v.z); o.w = f2bf(v.w);
        dst[off] = o;
    } else {
        int e = idx - 73728;                      // < 448*384
        if (e >= NCOMB * DI) return;
        int row = e / DI, k = e - row * DI;
        float v = 0.f;
        if (row < 384) {
            const float* dw = dt_w + row * DTR;
            #pragma unroll
            for (int r = 0; r < DTR; ++r) v += dw[r] * x_proj_w[r * DI + k];
        } else if (row < 416) {
            v = x_proj_w[(12 + (row - 384)) * DI + k];
        }
        wc[e] = f2bf(v);
    }
}

// ---------------------------------------------------------------------------
// Shared epilogue semantics:
// mode 0: N=768 split -> out0[row*384+col] raw (col<384),
//         col>=384 -> ((ushort*)out1)[row*384+col-384] = bf16(silu(v))
// mode 1: plain ((float*)out0)[row*N+col]
// mode 2: col<384 -> out0 = softplus(v+bias[col]);
//         col in [384,400): B_n -> ((float*)out1)[row*32 + (n&7)*4 + (n>>3)]
//         col in [400,416): C_n -> ((float*)out1)[row*32 + (n&7)*4 + 2 + (n>>3)]
// ---------------------------------------------------------------------------
__device__ __forceinline__ void gemm_epilogue(
    int mode, int row, int col, int N, float v,
    const float* __restrict__ bias,
    float* __restrict__ out0, void* __restrict__ out1)
{
    if (mode == 0) {
        if (col < 384) out0[(size_t)row * 384 + col] = v;
        else ((unsigned short*)out1)[(size_t)row * 384 + (col - 384)] = f2bf(silu_f(v));
    } else if (mode == 1) {
        out0[(size_t)row * N + col] = v;
    } else {
        if (col < 384) {
            float a = v + bias[col];
            out0[(size_t)row * 384 + col] = (a > 20.f) ? a : log1pf(__expf(a));
        } else if (col < 416) {
            int idx = col - 384;
            int pos = (idx < 16) ? ((idx & 7) * 4 + (idx >> 3))
                                 : (((idx - 16) & 7) * 4 + 2 + ((idx - 16) >> 3));
            ((float*)out1)[(size_t)row * 32 + pos] = v;
        }
    }
}

// ---------------------------------------------------------------------------
// bf16 MFMA GEMM, 64x64 tile, BK=64 (8 MFMA per barrier pair — halves
// barrier count vs BK=32; accumulation order per element unchanged).
// 256 threads; wave w -> rows w*16..w*16+15. K must be /64.
// ---------------------------------------------------------------------------
__global__ __launch_bounds__(256) void gemm_bf16(
    const unsigned short* __restrict__ A, const unsigned short* __restrict__ W,
    const float* __restrict__ bias,
    float* __restrict__ out0, void* __restrict__ out1,
    int M, int N, int K, int mode)
{
    __shared__ __align__(16) unsigned short sA[64 * SAROW];
    __shared__ __align__(16) unsigned short sB[64 * SAROW];
    const int bm = blockIdx.x * 64;
    const int bn = blockIdx.y * 64;
    const int tid  = threadIdx.x;
    const int wave = tid >> 6;
    const int lane = tid & 63;
    const int quad = lane >> 4;
    const int l16  = lane & 15;
    const int lrow = tid >> 2;        // 0..63
    const int lkof = (tid & 3) * 16;  // 0,16,32,48

    f32x4 acc[4];
    #pragma unroll
    for (int t = 0; t < 4; ++t) acc[t] = (f32x4)(0.f);

    const int arow = (wave * 16 + l16) * SAROW + quad * 8;

    for (int k0 = 0; k0 < K; k0 += 64) {
        const unsigned short* ap = &A[(size_t)(bm + lrow) * K + k0 + lkof];
        const unsigned short* wp = &W[(size_t)(bn + lrow) * K + k0 + lkof];
        *(bf16x8*)&sA[lrow * SAROW + lkof]     = *(const bf16x8*)ap;
        *(bf16x8*)&sA[lrow * SAROW + lkof + 8] = *(const bf16x8*)(ap + 8);
        *(bf16x8*)&sB[lrow * SAROW + lkof]     = *(const bf16x8*)wp;
        *(bf16x8*)&sB[lrow * SAROW + lkof + 8] = *(const bf16x8*)(wp + 8);
        __syncthreads();
        bf16x8 a0 = *(bf16x8*)&sA[arow];
        bf16x8 a1 = *(bf16x8*)&sA[arow + 32];
        #pragma unroll
        for (int t = 0; t < 4; ++t) {
            bf16x8 b0 = *(bf16x8*)&sB[(t * 16 + l16) * SAROW + quad * 8];
            bf16x8 b1 = *(bf16x8*)&sB[(t * 16 + l16) * SAROW + 32 + quad * 8];
            acc[t] = __builtin_amdgcn_mfma_f32_16x16x32_bf16(a0, b0, acc[t], 0, 0, 0);
            acc[t] = __builtin_amdgcn_mfma_f32_16x16x32_bf16(a1, b1, acc[t], 0, 0, 0);
        }
        __syncthreads();
    }

    #pragma unroll
    for (int t = 0; t < 4; ++t) {
        int col = bn + t * 16 + l16;
        #pragma unroll
        for (int r = 0; r < 4; ++r) {
            int row = bm + wave * 16 + quad * 4 + r;
            gemm_epilogue(mode, row, col, N, acc[t][r], bias, out0, out1);
        }
    }
}

// ---------------------------------------------------------------------------
// Dual GEMM, BK=64: z=0 -> xz = x @ W_in.T (mode 0, N=768); z=1 -> c =
// cond @ W_con.T (mode 1, N=384). fp32 A cast to bf16 during staging.
// ---------------------------------------------------------------------------
__global__ __launch_bounds__(256) void gemm_dual(
    const float* __restrict__ x, const float* __restrict__ cond,
    const unsigned short* __restrict__ w_in_bf,
    const unsigned short* __restrict__ w_con_bf,
    float* __restrict__ xa_pre, unsigned short* __restrict__ z_bf,
    float* __restrict__ c_pre)
{
    const int zz = blockIdx.z;
    if (zz == 1 && blockIdx.y >= 6) return;
    const float* A = zz ? cond : x;
    const unsigned short* W = zz ? w_con_bf : w_in_bf;
    float* out0 = zz ? c_pre : xa_pre;
    const int mode = zz ? 1 : 0;
    const int N = zz ? 384 : 768;

    __shared__ __align__(16) unsigned short sA[64 * SAROW];
    __shared__ __align__(16) unsigned short sB[64 * SAROW];
    const int bm = blockIdx.x * 64;
    const int bn = blockIdx.y * 64;
    const int tid  = threadIdx.x;
    const int wave = tid >> 6;
    const int lane = tid & 63;
    const int quad = lane >> 4;
    const int l16  = lane & 15;
    const int lrow = tid >> 2;
    const int lkof = (tid & 3) * 16;

    f32x4 acc[4];
    #pragma unroll
    for (int t = 0; t < 4; ++t) acc[t] = (f32x4)(0.f);

    const int arow = (wave * 16 + l16) * SAROW + quad * 8;

    for (int k0 = 0; k0 < DM; k0 += 64) {
        const float* ap = &A[(size_t)(bm + lrow) * DM + k0 + lkof];
        float4 a0 = *(const float4*)ap;
        float4 a1 = *(const float4*)(ap + 4);
        float4 a2 = *(const float4*)(ap + 8);
        float4 a3 = *(const float4*)(ap + 12);
        *(bf16x8*)&sA[lrow * SAROW + lkof]     = f2bf8(a0, a1);
        *(bf16x8*)&sA[lrow * SAROW + lkof + 8] = f2bf8(a2, a3);
        const unsigned short* wp = &W[(size_t)(bn + lrow) * DM + k0 + lkof];
        *(bf16x8*)&sB[lrow * SAROW + lkof]     = *(const bf16x8*)wp;
        *(bf16x8*)&sB[lrow * SAROW + lkof + 8] = *(const bf16x8*)(wp + 8);
        __syncthreads();
        bf16x8 av0 = *(bf16x8*)&sA[arow];
        bf16x8 av1 = *(bf16x8*)&sA[arow + 32];
        #pragma unroll
        for (int t = 0; t < 4; ++t) {
            bf16x8 b0 = *(bf16x8*)&sB[(t * 16 + l16) * SAROW + quad * 8];
            bf16x8 b1 = *(bf16x8*)&sB[(t * 16 + l16) * SAROW + 32 + quad * 8];
            acc[t] = __builtin_amdgcn_mfma_f32_16x16x32_bf16(av0, b0, acc[t], 0, 0, 0);
            acc[t] = __builtin_amdgcn_mfma_f32_16x16x32_bf16(av1, b1, acc[t], 0, 0, 0);
        }
        __syncthreads();
    }

    #pragma unroll
    for (int t = 0; t < 4; ++t) {
        int col = bn + t * 16 + l16;
        #pragma unroll
        for (int r = 0; r < 4; ++r) {
            int row = bm + wave * 16 + quad * 4 + r;
            gemm_epilogue(mode, row, col, N, acc[t][r], nullptr, out0, (void*)z_bf);
        }
    }
}

// ---------------------------------------------------------------------------
// Fused depthwise 3x3 convs + bias + silu; writes xs (fp32) and
// s = silu(conv_x)+silu(conv_c) as bf16, SCATTERED to scan order.
// 32-channel groups; grid (64, 12, B).
// ---------------------------------------------------------------------------
__global__ __launch_bounds__(256) void dwconv2_scatter(
    const float* __restrict__ xin, const float* __restrict__ cin,
    const float* __restrict__ wx, const float* __restrict__ bx,
    const float* __restrict__ wc, const float* __restrict__ bc,
    const int* __restrict__ rev_scan_path,
    float* __restrict__ xs_buf, unsigned short* __restrict__ s_bf)
{
    const int tile = blockIdx.x;
    const int c0   = blockIdx.y * 32;
    const int b    = blockIdx.z;
    const int h0 = (tile >> 3) * 8, w0 = (tile & 7) * 8;
    __shared__ float smx[10 * 10 * 32];
    __shared__ float smc[10 * 10 * 32];
    __shared__ int   jtile[64];

    for (int idx = threadIdx.x; idx < 3200; idx += 256) {
        int pix = idx >> 5, ch = idx & 31;
        int py = pix / 10, px = pix - py * 10;
        int gh = h0 + py - 1, gw = w0 + px - 1;
        float vx = 0.f, vc = 0.f;
        if (gh >= 0 && gh < 64 && gw >= 0 && gw < 64) {
            size_t g = ((size_t)(b * LL + gh * 64 + gw)) * DI + c0 + ch;
            vx = xin[g]; vc = cin[g];
        }
        smx[idx] = vx; smc[idx] = vc;
    }
    if (threadIdx.x < 64) {
        int l = (h0 + (threadIdx.x >> 3)) * 64 + (w0 + (threadIdx.x & 7));
        jtile[threadIdx.x] = rev_scan_path[l];
    }
    __syncthreads();

    const int ch = threadIdx.x & 31;
    const int pq = threadIdx.x >> 5;   // 0..7
    float wrx[9], wrc[9];
    #pragma unroll
    for (int k = 0; k < 9; ++k) {
        wrx[k] = wx[(c0 + ch) * 9 + k];
        wrc[k] = wc[(c0 + ch) * 9 + k];
    }
    const float bvx = bx[c0 + ch];
    const float bvc = bc[c0 + ch];

    #pragma unroll
    for (int i = 0; i < 8; ++i) {
        int p  = pq * 8 + i;           // 0..63
        int ph = p >> 3, pw = p & 7;
        float ax = bvx, ac = bvc;
        #pragma unroll
        for (int ki = 0; ki < 3; ++ki)
            #pragma unroll
            for (int kj = 0; kj < 3; ++kj) {
                int si = ((ph + ki) * 10 + (pw + kj)) * 32 + ch;
                ax += wrx[ki * 3 + kj] * smx[si];
                ac += wrc[ki * 3 + kj] * smc[si];
            }
        float xv = silu_f(ax);
        float sv = xv + silu_f(ac);
        size_t o = ((size_t)(b * LL + jtile[p])) * DI + c0 + ch;
        xs_buf[o] = xv;
        s_bf[o]   = f2bf(sv);
    }
}

// ---------------------------------------------------------------------------
// Pass A: per-chunk composite, register-prefetch. 8 lanes/channel, 2 states
// per lane. grid (NCHUNK, DI/32, BB). Composite layout CHUNK-MAJOR: block's
// 256 lanes write one contiguous 2 KB slab (coalesced); pass C's backward
// fold reads coalesce across lanes. Chunk decay = exp(Av * sum(delta)).
// ---------------------------------------------------------------------------
__global__ __launch_bounds__(256) void scan_chunkA(
    const float* __restrict__ xs, const float* __restrict__ delta,
    const float* __restrict__ btct, const float* __restrict__ A_logs,
    float* __restrict__ chunkA, float* __restrict__ chunkB)
{
    const int c = blockIdx.x;
    const int g = blockIdx.y;
    const int b = blockIdx.z;
    const int t = threadIdx.x;
    const int grp = t >> 3, p = t & 7;
    const int d = g * 32 + grp;
    const float Av0 = -__expf(A_logs[d * NS + p]);
    const float Av1 = -__expf(A_logs[d * NS + p + 8]);
    const int j0 = c * LCHUNK;

    const float*  dl = delta + ((size_t)b * LL + j0) * DI + d;
    const float*  ul = xs    + ((size_t)b * LL + j0) * DI + d;
    const float2* bl = (const float2*)btct + ((size_t)b * LL + j0) * 16 + p * 2;

    float h0 = 0.f, h1 = 0.f, Sd = 0.f;
    float dv[4], uv[4]; float2 bv[4];
    #pragma unroll
    for (int q = 0; q < 4; ++q) {
        dv[q] = dl[(size_t)q * DI]; uv[q] = ul[(size_t)q * DI]; bv[q] = bl[(size_t)q * 16];
    }
    for (int j = 0; j < LCHUNK; j += 4) {
        float nd[4], nu[4]; float2 nb[4];
        if (j + 4 < LCHUNK) {
            #pragma unroll
            for (int q = 0; q < 4; ++q) {
                int jj = j + 4 + q;
                nd[q] = dl[(size_t)jj * DI]; nu[q] = ul[(size_t)jj * DI]; nb[q] = bl[(size_t)jj * 16];
            }
        }
        #pragma unroll
        for (int q = 0; q < 4; ++q) {
            float e0 = __expf(dv[q] * Av0);
            float e1 = __expf(dv[q] * Av1);
            float du = dv[q] * uv[q];
            h0 = e0 * h0 + bv[q].x * du;
            h1 = e1 * h1 + bv[q].y * du;
            Sd += dv[q];
        }
        #pragma unroll
        for (int q = 0; q < 4; ++q) { dv[q]=nd[q]; uv[q]=nu[q]; bv[q]=nb[q]; }
    }
    size_t idx = (size_t)c * CSTRIDE + ((size_t)b * DI + d) * 8 + p;
    ((float2*)chunkA)[idx] = make_float2(__expf(Sd * Av0), __expf(Sd * Av1));
    ((float2*)chunkB)[idx] = make_float2(h0, h1);
}

// ---------------------------------------------------------------------------
// Pass C: local scan seeded by an INLINE backward fold over the chunk-major
// composites (coalesced 2 KB/wave reads per fold step, early exit once the
// running decay product underflows — depth ~3-4).
// ---------------------------------------------------------------------------
__global__ __launch_bounds__(256) void scan_chunkC(
    const float* __restrict__ xs, const float* __restrict__ delta,
    const float* __restrict__ btct,
    const float* __restrict__ A_logs, const float* __restrict__ Ds,
    const float* __restrict__ chunkA, const float* __restrict__ chunkB,
    float* __restrict__ yt)
{
    const int c = blockIdx.x;
    const int g = blockIdx.y;
    const int b = blockIdx.z;
    const int t = threadIdx.x;
    const int grp = t >> 3, p = t & 7;
    const int d = g * 32 + grp;
    const float Av0 = -__expf(A_logs[d * NS + p]);
    const float Av1 = -__expf(A_logs[d * NS + p + 8]);
    const float Dv = Ds[d];
    const int j0 = c * LCHUNK;

    const float*  dl  = delta + ((size_t)b * LL + j0) * DI + d;
    const float*  ul  = xs    + ((size_t)b * LL + j0) * DI + d;
    const float4* bcl = (const float4*)btct + ((size_t)b * LL + j0) * 8 + p;
    float* yl = yt + ((size_t)b * LL + j0) * DI + d;

    const size_t off = ((size_t)b * DI + d) * 8 + p;
    const float2* A2 = (const float2*)chunkA;
    const float2* B2 = (const float2*)chunkB;
    float h0 = 0.f, h1 = 0.f, P0 = 1.f, P1 = 1.f;
    for (int i = c - 1; i >= 0; --i) {
        size_t ix = (size_t)i * CSTRIDE + off;
        float2 a = A2[ix], bv = B2[ix];
        h0 += P0 * bv.x;  h1 += P1 * bv.y;
        P0 *= a.x;        P1 *= a.y;
        if (fmaxf(fabsf(P0), fabsf(P1)) < 1e-30f) break;
    }

    float dv[4], uv[4]; float4 bc[4];
    #pragma unroll
    for (int q = 0; q < 4; ++q) {
        dv[q] = dl[(size_t)q * DI]; uv[q] = ul[(size_t)q * DI]; bc[q] = bcl[(size_t)q * 8];
    }
    for (int j = 0; j < LCHUNK; j += 4) {
        float nd[4], nu[4]; float4 nbc[4];
        if (j + 4 < LCHUNK) {
            #pragma unroll
            for (int q = 0; q < 4; ++q) {
                int jj = j + 4 + q;
                nd[q] = dl[(size_t)jj * DI]; nu[q] = ul[(size_t)jj * DI]; nbc[q] = bcl[(size_t)jj * 8];
            }
        }
        #pragma unroll
        for (int q = 0; q < 4; ++q) {
            float e0 = __expf(dv[q] * Av0);
            float e1 = __expf(dv[q] * Av1);
            float du = dv[q] * uv[q];
            h0 = e0 * h0 + bc[q].x * du;
            h1 = e1 * h1 + bc[q].y * du;
            float acc = h0 * bc[q].z + h1 * bc[q].w;
            acc += __shfl_xor(acc, 4, 8);
            acc += __shfl_xor(acc, 2, 8);
            acc += __shfl_xor(acc, 1, 8);
            if (p == 0) yl[(size_t)(j + q) * DI] = acc + uv[q] * Dv;
        }
        #pragma unroll
        for (int q = 0; q < 4; ++q) { dv[q]=nd[q]; uv[q]=nu[q]; bc[q]=nbc[q]; }
    }
}

// ---------------------------------------------------------------------------
// LayerNorm over d (384) + affine + z-mul (z in bf16); unpermute folded into
// write; yn out in bf16.
// ---------------------------------------------------------------------------
__global__ __launch_bounds__(128) void ln_mul(
    const float* __restrict__ yt, const unsigned short* __restrict__ z,
    const int* __restrict__ scan_path,
    const float* __restrict__ ln_w, const float* __restrict__ ln_b,
    unsigned short* __restrict__ yn)
{
    const int j = blockIdx.x;
    const int b = blockIdx.y;
    const int l = scan_path[j];
    const int t = threadIdx.x;
    const float* row = yt + ((size_t)(b * LL + j)) * DI;
    float v0 = row[t], v1 = row[t + 128], v2 = row[t + 256];
    float s  = v0 + v1 + v2;
    float s2 = v0*v0 + v1*v1 + v2*v2;
    #pragma unroll
    for (int off = 32; off > 0; off >>= 1) {
        s  += __shfl_down(s, off);
        s2 += __shfl_down(s2, off);
    }
    __shared__ float red[4];
    if ((t & 63) == 0) { red[(t >> 6) * 2] = s; red[(t >> 6) * 2 + 1] = s2; }
    __syncthreads();
    float S  = red[0] + red[2];
    float S2 = red[1] + red[3];
    float mu  = S * (1.0f / DI);
    float var = S2 * (1.0f / DI) - mu * mu;
    float inv = rsqrtf(var + 1e-5f);

    const unsigned short* zr = z + ((size_t)(b * LL + l)) * DI;
    unsigned short* o = yn + ((size_t)(b * LL + l)) * DI;
    o[t]       = f2bf(((v0 - mu) * inv * ln_w[t]       + ln_b[t])       * bf2f(zr[t]));
    o[t + 128] = f2bf(((v1 - mu) * inv * ln_w[t + 128] + ln_b[t + 128]) * bf2f(zr[t + 128]));
    o[t + 256] = f2bf(((v2 - mu) * inv * ln_w[t + 256] + ln_b[t + 256]) * bf2f(zr[t + 256]));
}

// ---------------------------------------------------------------------------
extern "C" void kernel_launch(void* const* d_in, const int* in_sizes, int n_in,
                              void* d_out, int out_size, void* d_ws, size_t ws_size,
                              hipStream_t stream) {
    const float* x          = (const float*)d_in[0];
    const float* cond       = (const float*)d_in[1];
    const float* W_in       = (const float*)d_in[2];
    const float* W_con      = (const float*)d_in[3];
    const float* conv_w     = (const float*)d_in[4];
    const float* conv_b     = (const float*)d_in[5];
    const float* con_conv_w = (const float*)d_in[6];
    const float* con_conv_b = (const float*)d_in[7];
    const float* x_proj_w   = (const float*)d_in[8];
    const float* dt_proj_w  = (const float*)d_in[9];
    const float* dt_proj_b  = (const float*)d_in[10];
    const float* A_logs     = (const float*)d_in[11];
    const float* Ds         = (const float*)d_in[12];
    const float* ln_w       = (const float*)d_in[13];
    const float* ln_b       = (const float*)d_in[14];
    const float* W_out      = (const float*)d_in[15];
    const int*   scan_path  = (const int*)d_in[16];
    const int*   rev_path   = (const int*)d_in[17];

    float* ws = (float*)d_ws;
    const size_t S  = (size_t)BB * LL * DI;            // 3,145,728 floats
    const size_t SC = (size_t)NCHUNK * BB * DI * NS;   // 1,572,864 floats
    float* xa_pre  = ws + 0 * S;                       // reused later as yt
    float* zslab   = ws + 1 * S;                       // z_bf (ushort, half used)
    float* c_pre   = ws + 2 * S;                       // reused as yn_bf
    float* xs_buf  = ws + 3 * S;
    float* dl_buf  = ws + 4 * S;
    float* btct    = ws + 5 * S;                       // BB*LL*32 floats, packed
    float* chunkA  = btct + (size_t)BB * LL * 32;
    float* chunkB  = chunkA + SC;
    float* bfpool  = chunkB + SC;                      // bf16 staging area

    unsigned short* z_bf     = (unsigned short*)zslab;             // ROWS*DI
    unsigned short* s_bf     = (unsigned short*)bfpool;            // ROWS*DI
    unsigned short* w_in_bf  = s_bf + (size_t)ROWS * DI;           // 768*192
    unsigned short* w_con_bf = w_in_bf + 768 * DM;                 // 384*192
    unsigned short* w_out_bf = w_con_bf + 384 * DM;                // 192*384
    unsigned short* wcomb_bf = w_out_bf + 192 * DI;                // 448*384
    unsigned short* yn_bf    = (unsigned short*)c_pre;             // ROWS*DI
    float* yt = xa_pre;

    // 0) weight prep (casts + combined weight), one launch
    prep_weights<<<(73728 + NCOMB * DI + 255) / 256, 256, 0, stream>>>(
        W_in, W_con, W_out, x_proj_w, dt_proj_w,
        w_in_bf, w_con_bf, w_out_bf, wcomb_bf);

    // 1+2) dual GEMM: xz = x @ W_in.T (split, z->bf16 silu) AND c = cond @ W_con.T
    gemm_dual<<<dim3(ROWS / 64, 12, 2), 256, 0, stream>>>(
        x, cond, w_in_bf, w_con_bf, xa_pre, z_bf, c_pre);
    // 3) fused depthwise convs + silu + scatter to scan order (32-ch groups)
    dwconv2_scatter<<<dim3(64, 12, BB), 256, 0, stream>>>(
        xa_pre, c_pre, conv_w, conv_b, con_conv_w, con_conv_b,
        rev_path, xs_buf, s_bf);
    // 4) combined GEMM: delta (softplus) + packed btct
    gemm_bf16<<<dim3(ROWS / 64, NCOMB / 64), 256, 0, stream>>>(
        s_bf, wcomb_bf, dt_proj_b, dl_buf, (void*)btct, ROWS, NCOMB, DI, 2);
    // 5) chunked parallel scan: pass A, then pass C with coalesced inline fold
    scan_chunkA<<<dim3(NCHUNK, DI / 32, BB), 256, 0, stream>>>(
        xs_buf, dl_buf, btct, A_logs, chunkA, chunkB);
    scan_chunkC<<<dim3(NCHUNK, DI / 32, BB), 256, 0, stream>>>(
        xs_buf, dl_buf, btct, A_logs, Ds, chunkA, chunkB, yt);
    // 6) LN + z-mul (unpermute folded in), yn in bf16
    ln_mul<<<dim3(LL, BB), 128, 0, stream>>>(yt, z_bf, scan_path, ln_w, ln_b, yn_bf);
    // 7) out = yn @ W_out.T
    gemm_bf16<<<dim3(ROWS / 64, 192 / 64), 256, 0, stream>>>(
        yn_bf, w_out_bf, nullptr, (float*)d_out, nullptr, ROWS, DM, DI, 1);
}

// Round 16
// 206.448 us; speedup vs baseline: 1.0323x; 1.0323x over previous
//
#include <hip/hip_runtime.h>
#include <math.h>

// Problem constants
#define BB 2
#define HH 64
#define WW 64
#define DM 192
#define DI 384
#define NS 16
#define DTR 12
#define LL 4096
#define ROWS (BB*LL)   // 8192
#define NCHUNK 128
#define LCHUNK 32      // NCHUNK*LCHUNK == LL
#define NCOMB 448      // padded combined-weight rows (416 real)
#define CSTRIDE ((size_t)BB * DI * 8)   // float2 elems per chunk slab

typedef __attribute__((ext_vector_type(8))) short bf16x8;
typedef __attribute__((ext_vector_type(4))) float f32x4;

__device__ __forceinline__ float silu_f(float v) {
    return v / (1.0f + __expf(-v));
}

// fp32 -> bf16 (RNE) bit trick
__device__ __forceinline__ unsigned short f2bf(float f) {
    union { float f; unsigned int u; } c; c.f = f;
    unsigned int u = c.u;
    u += 0x7fffu + ((u >> 16) & 1u);
    return (unsigned short)(u >> 16);
}
__device__ __forceinline__ float bf2f(unsigned short h) {
    union { unsigned int u; float f; } c; c.u = ((unsigned int)h) << 16;
    return c.f;
}

__device__ __forceinline__ bf16x8 f2bf8(float4 a, float4 b) {
    bf16x8 r;
    r[0] = (short)f2bf(a.x); r[1] = (short)f2bf(a.y);
    r[2] = (short)f2bf(a.z); r[3] = (short)f2bf(a.w);
    r[4] = (short)f2bf(b.x); r[5] = (short)f2bf(b.y);
    r[6] = (short)f2bf(b.z); r[7] = (short)f2bf(b.w);
    return r;
}

// ---------------------------------------------------------------------------
// One prep kernel: cast W_in/W_con/W_out to bf16 AND build combined weight
// Wc[448][384] (rows 0..383 = dt_w @ x_proj_w[:12], 384..415 = B/C rows).
// ---------------------------------------------------------------------------
__global__ __launch_bounds__(256) void prep_weights(
    const float* __restrict__ w_in, const float* __restrict__ w_con,
    const float* __restrict__ w_out,
    const float* __restrict__ x_proj_w, const float* __restrict__ dt_w,
    unsigned short* __restrict__ w_in_bf, unsigned short* __restrict__ w_con_bf,
    unsigned short* __restrict__ w_out_bf, unsigned short* __restrict__ wc)
{
    int idx = blockIdx.x * 256 + threadIdx.x;
    if (idx < 73728) {
        const float4* src; ushort4* dst; int off;
        if (idx < 36864)      { src = (const float4*)w_in;  dst = (ushort4*)w_in_bf;  off = idx; }
        else if (idx < 55296) { src = (const float4*)w_con; dst = (ushort4*)w_con_bf; off = idx - 36864; }
        else                  { src = (const float4*)w_out; dst = (ushort4*)w_out_bf; off = idx - 55296; }
        float4 v = src[off];
        ushort4 o;
        o.x = f2bf(v.x); o.y = f2bf(v.y); o.z = f2bf(v.z); o.w = f2bf(v.w);
        dst[off] = o;
    } else {
        int e = idx - 73728;                      // < 448*384
        if (e >= NCOMB * DI) return;
        int row = e / DI, k = e - row * DI;
        float v = 0.f;
        if (row < 384) {
            const float* dw = dt_w + row * DTR;
            #pragma unroll
            for (int r = 0; r < DTR; ++r) v += dw[r] * x_proj_w[r * DI + k];
        } else if (row < 416) {
            v = x_proj_w[(12 + (row - 384)) * DI + k];
        }
        wc[e] = f2bf(v);
    }
}

// ---------------------------------------------------------------------------
// Shared epilogue semantics (gemm_bf16 only):
// mode 1: plain ((float*)out0)[row*N+col]
// mode 2: col<384 -> out0 = softplus(v+bias[col]);
//         col in [384,400): B_n -> ((float*)out1)[row*32 + (n&7)*4 + (n>>3)]
//         col in [400,416): C_n -> ((float*)out1)[row*32 + (n&7)*4 + 2 + (n>>3)]
// ---------------------------------------------------------------------------
__device__ __forceinline__ void gemm_epilogue(
    int mode, int row, int col, int N, float v,
    const float* __restrict__ bias,
    float* __restrict__ out0, void* __restrict__ out1)
{
    if (mode == 1) {
        out0[(size_t)row * N + col] = v;
    } else {
        if (col < 384) {
            float a = v + bias[col];
            out0[(size_t)row * 384 + col] = (a > 20.f) ? a : log1pf(__expf(a));
        } else if (col < 416) {
            int idx = col - 384;
            int pos = (idx < 16) ? ((idx & 7) * 4 + (idx >> 3))
                                 : (((idx - 16) & 7) * 4 + 2 + ((idx - 16) >> 3));
            ((float*)out1)[(size_t)row * 32 + pos] = v;
        }
    }
}

// ---------------------------------------------------------------------------
// bf16 MFMA GEMM, 64x64 tile, BK=32, 256 threads. A is bf16. (r14 body —
// BK=64 experiment regressed; BK=32 is the sweet spot for these shapes.)
// ---------------------------------------------------------------------------
__global__ __launch_bounds__(256) void gemm_bf16(
    const unsigned short* __restrict__ A, const unsigned short* __restrict__ W,
    const float* __restrict__ bias,
    float* __restrict__ out0, void* __restrict__ out1,
    int M, int N, int K, int mode)
{
    __shared__ __align__(16) unsigned short sA[64 * 40];
    __shared__ __align__(16) unsigned short sB[64 * 40];
    const int bm = blockIdx.x * 64;
    const int bn = blockIdx.y * 64;
    const int tid  = threadIdx.x;
    const int wave = tid >> 6;
    const int lane = tid & 63;
    const int quad = lane >> 4;
    const int l16  = lane & 15;
    const int lrow = tid >> 2;
    const int lkof = (tid & 3) * 8;

    f32x4 acc[4];
    #pragma unroll
    for (int t = 0; t < 4; ++t) acc[t] = (f32x4)(0.f);

    const int arow = (wave * 16 + l16) * 40 + quad * 8;

    for (int k0 = 0; k0 < K; k0 += 32) {
        *(bf16x8*)&sA[lrow * 40 + lkof] =
            *(const bf16x8*)&A[(size_t)(bm + lrow) * K + k0 + lkof];
        *(bf16x8*)&sB[lrow * 40 + lkof] =
            *(const bf16x8*)&W[(size_t)(bn + lrow) * K + k0 + lkof];
        __syncthreads();
        bf16x8 a = *(bf16x8*)&sA[arow];
        #pragma unroll
        for (int t = 0; t < 4; ++t) {
            bf16x8 b = *(bf16x8*)&sB[(t * 16 + l16) * 40 + quad * 8];
            acc[t] = __builtin_amdgcn_mfma_f32_16x16x32_bf16(a, b, acc[t], 0, 0, 0);
        }
        __syncthreads();
    }

    #pragma unroll
    for (int t = 0; t < 4; ++t) {
        int col = bn + t * 16 + l16;
        #pragma unroll
        for (int r = 0; r < 4; ++r) {
            int row = bm + wave * 16 + quad * 4 + r;
            gemm_epilogue(mode, row, col, N, acc[t][r], bias, out0, out1);
        }
    }
}

// ---------------------------------------------------------------------------
// Dual GEMM, BK=32: z=0 -> xz = x @ W_in.T (xa->bf16, z->bf16 silu, N=768);
// z=1 -> c = cond @ W_con.T (c->bf16, N=384). fp32 A cast to bf16 during
// staging. All outputs bf16: the conv is the only consumer and its output
// is rounded to bf16 anyway — this halves the conv-input HBM traffic.
// ---------------------------------------------------------------------------
__global__ __launch_bounds__(256) void gemm_dual(
    const float* __restrict__ x, const float* __restrict__ cond,
    const unsigned short* __restrict__ w_in_bf,
    const unsigned short* __restrict__ w_con_bf,
    unsigned short* __restrict__ xa_bf, unsigned short* __restrict__ z_bf,
    unsigned short* __restrict__ c_bf)
{
    const int zz = blockIdx.z;
    if (zz == 1 && blockIdx.y >= 6) return;
    const float* A = zz ? cond : x;
    const unsigned short* W = zz ? w_con_bf : w_in_bf;

    __shared__ __align__(16) unsigned short sA[64 * 40];
    __shared__ __align__(16) unsigned short sB[64 * 40];
    const int bm = blockIdx.x * 64;
    const int bn = blockIdx.y * 64;
    const int tid  = threadIdx.x;
    const int wave = tid >> 6;
    const int lane = tid & 63;
    const int quad = lane >> 4;
    const int l16  = lane & 15;
    const int lrow = tid >> 2;
    const int lkof = (tid & 3) * 8;

    f32x4 acc[4];
    #pragma unroll
    for (int t = 0; t < 4; ++t) acc[t] = (f32x4)(0.f);

    const int arow = (wave * 16 + l16) * 40 + quad * 8;

    for (int k0 = 0; k0 < DM; k0 += 32) {
        const float* ap = &A[(size_t)(bm + lrow) * DM + k0 + lkof];
        float4 a0 = *(const float4*)ap;
        float4 a1 = *(const float4*)(ap + 4);
        *(bf16x8*)&sA[lrow * 40 + lkof] = f2bf8(a0, a1);
        *(bf16x8*)&sB[lrow * 40 + lkof] =
            *(const bf16x8*)&W[(size_t)(bn + lrow) * DM + k0 + lkof];
        __syncthreads();
        bf16x8 a = *(bf16x8*)&sA[arow];
        #pragma unroll
        for (int t = 0; t < 4; ++t) {
            bf16x8 b = *(bf16x8*)&sB[(t * 16 + l16) * 40 + quad * 8];
            acc[t] = __builtin_amdgcn_mfma_f32_16x16x32_bf16(a, b, acc[t], 0, 0, 0);
        }
        __syncthreads();
    }

    #pragma unroll
    for (int t = 0; t < 4; ++t) {
        int col = bn + t * 16 + l16;
        #pragma unroll
        for (int r = 0; r < 4; ++r) {
            int row = bm + wave * 16 + quad * 4 + r;
            float v = acc[t][r];
            if (zz == 0) {
                if (col < 384) xa_bf[(size_t)row * 384 + col] = f2bf(v);
                else           z_bf[(size_t)row * 384 + (col - 384)] = f2bf(silu_f(v));
            } else {
                c_bf[(size_t)row * 384 + col] = f2bf(v);
            }
        }
    }
}

// ---------------------------------------------------------------------------
// Fused depthwise 3x3 convs + bias + silu; inputs bf16, math fp32; writes
// xs (fp32) and s = silu(conv_x)+silu(conv_c) as bf16, SCATTERED to scan
// order. 32-channel groups; grid (64, 12, B).
// ---------------------------------------------------------------------------
__global__ __launch_bounds__(256) void dwconv2_scatter(
    const unsigned short* __restrict__ xin, const unsigned short* __restrict__ cin,
    const float* __restrict__ wx, const float* __restrict__ bx,
    const float* __restrict__ wc, const float* __restrict__ bc,
    const int* __restrict__ rev_scan_path,
    float* __restrict__ xs_buf, unsigned short* __restrict__ s_bf)
{
    const int tile = blockIdx.x;
    const int c0   = blockIdx.y * 32;
    const int b    = blockIdx.z;
    const int h0 = (tile >> 3) * 8, w0 = (tile & 7) * 8;
    __shared__ float smx[10 * 10 * 32];
    __shared__ float smc[10 * 10 * 32];
    __shared__ int   jtile[64];

    for (int idx = threadIdx.x; idx < 3200; idx += 256) {
        int pix = idx >> 5, ch = idx & 31;
        int py = pix / 10, px = pix - py * 10;
        int gh = h0 + py - 1, gw = w0 + px - 1;
        float vx = 0.f, vc = 0.f;
        if (gh >= 0 && gh < 64 && gw >= 0 && gw < 64) {
            size_t g = ((size_t)(b * LL + gh * 64 + gw)) * DI + c0 + ch;
            vx = bf2f(xin[g]); vc = bf2f(cin[g]);
        }
        smx[idx] = vx; smc[idx] = vc;
    }
    if (threadIdx.x < 64) {
        int l = (h0 + (threadIdx.x >> 3)) * 64 + (w0 + (threadIdx.x & 7));
        jtile[threadIdx.x] = rev_scan_path[l];
    }
    __syncthreads();

    const int ch = threadIdx.x & 31;
    const int pq = threadIdx.x >> 5;   // 0..7
    float wrx[9], wrc[9];
    #pragma unroll
    for (int k = 0; k < 9; ++k) {
        wrx[k] = wx[(c0 + ch) * 9 + k];
        wrc[k] = wc[(c0 + ch) * 9 + k];
    }
    const float bvx = bx[c0 + ch];
    const float bvc = bc[c0 + ch];

    #pragma unroll
    for (int i = 0; i < 8; ++i) {
        int p  = pq * 8 + i;           // 0..63
        int ph = p >> 3, pw = p & 7;
        float ax = bvx, ac = bvc;
        #pragma unroll
        for (int ki = 0; ki < 3; ++ki)
            #pragma unroll
            for (int kj = 0; kj < 3; ++kj) {
                int si = ((ph + ki) * 10 + (pw + kj)) * 32 + ch;
                ax += wrx[ki * 3 + kj] * smx[si];
                ac += wrc[ki * 3 + kj] * smc[si];
            }
        float xv = silu_f(ax);
        float sv = xv + silu_f(ac);
        size_t o = ((size_t)(b * LL + jtile[p])) * DI + c0 + ch;
        xs_buf[o] = xv;
        s_bf[o]   = f2bf(sv);
    }
}

// ---------------------------------------------------------------------------
// Pass A: per-chunk composite, register-prefetch. 8 lanes/channel, 2 states
// per lane. grid (NCHUNK, DI/32, BB). Composite layout CHUNK-MAJOR: block's
// 256 lanes write one contiguous 2 KB slab (coalesced); pass C's backward
// fold reads coalesce across lanes. Chunk decay = exp(Av * sum(delta)).
// ---------------------------------------------------------------------------
__global__ __launch_bounds__(256) void scan_chunkA(
    const float* __restrict__ xs, const float* __restrict__ delta,
    const float* __restrict__ btct, const float* __restrict__ A_logs,
    float* __restrict__ chunkA, float* __restrict__ chunkB)
{
    const int c = blockIdx.x;
    const int g = blockIdx.y;
    const int b = blockIdx.z;
    const int t = threadIdx.x;
    const int grp = t >> 3, p = t & 7;
    const int d = g * 32 + grp;
    const float Av0 = -__expf(A_logs[d * NS + p]);
    const float Av1 = -__expf(A_logs[d * NS + p + 8]);
    const int j0 = c * LCHUNK;

    const float*  dl = delta + ((size_t)b * LL + j0) * DI + d;
    const float*  ul = xs    + ((size_t)b * LL + j0) * DI + d;
    const float2* bl = (const float2*)btct + ((size_t)b * LL + j0) * 16 + p * 2;

    float h0 = 0.f, h1 = 0.f, Sd = 0.f;
    float dv[4], uv[4]; float2 bv[4];
    #pragma unroll
    for (int q = 0; q < 4; ++q) {
        dv[q] = dl[(size_t)q * DI]; uv[q] = ul[(size_t)q * DI]; bv[q] = bl[(size_t)q * 16];
    }
    for (int j = 0; j < LCHUNK; j += 4) {
        float nd[4], nu[4]; float2 nb[4];
        if (j + 4 < LCHUNK) {
            #pragma unroll
            for (int q = 0; q < 4; ++q) {
                int jj = j + 4 + q;
                nd[q] = dl[(size_t)jj * DI]; nu[q] = ul[(size_t)jj * DI]; nb[q] = bl[(size_t)jj * 16];
            }
        }
        #pragma unroll
        for (int q = 0; q < 4; ++q) {
            float e0 = __expf(dv[q] * Av0);
            float e1 = __expf(dv[q] * Av1);
            float du = dv[q] * uv[q];
            h0 = e0 * h0 + bv[q].x * du;
            h1 = e1 * h1 + bv[q].y * du;
            Sd += dv[q];
        }
        #pragma unroll
        for (int q = 0; q < 4; ++q) { dv[q]=nd[q]; uv[q]=nu[q]; bv[q]=nb[q]; }
    }
    size_t idx = (size_t)c * CSTRIDE + ((size_t)b * DI + d) * 8 + p;
    ((float2*)chunkA)[idx] = make_float2(__expf(Sd * Av0), __expf(Sd * Av1));
    ((float2*)chunkB)[idx] = make_float2(h0, h1);
}

// ---------------------------------------------------------------------------
// Pass C: local scan seeded by an INLINE backward fold over the chunk-major
// composites (coalesced 2 KB/wave reads per fold step, early exit once the
// running decay product underflows — depth ~3-4).
// ---------------------------------------------------------------------------
__global__ __launch_bounds__(256) void scan_chunkC(
    const float* __restrict__ xs, const float* __restrict__ delta,
    const float* __restrict__ btct,
    const float* __restrict__ A_logs, const float* __restrict__ Ds,
    const float* __restrict__ chunkA, const float* __restrict__ chunkB,
    float* __restrict__ yt)
{
    const int c = blockIdx.x;
    const int g = blockIdx.y;
    const int b = blockIdx.z;
    const int t = threadIdx.x;
    const int grp = t >> 3, p = t & 7;
    const int d = g * 32 + grp;
    const float Av0 = -__expf(A_logs[d * NS + p]);
    const float Av1 = -__expf(A_logs[d * NS + p + 8]);
    const float Dv = Ds[d];
    const int j0 = c * LCHUNK;

    const float*  dl  = delta + ((size_t)b * LL + j0) * DI + d;
    const float*  ul  = xs    + ((size_t)b * LL + j0) * DI + d;
    const float4* bcl = (const float4*)btct + ((size_t)b * LL + j0) * 8 + p;
    float* yl = yt + ((size_t)b * LL + j0) * DI + d;

    const size_t off = ((size_t)b * DI + d) * 8 + p;
    const float2* A2 = (const float2*)chunkA;
    const float2* B2 = (const float2*)chunkB;
    float h0 = 0.f, h1 = 0.f, P0 = 1.f, P1 = 1.f;
    for (int i = c - 1; i >= 0; --i) {
        size_t ix = (size_t)i * CSTRIDE + off;
        float2 a = A2[ix], bv = B2[ix];
        h0 += P0 * bv.x;  h1 += P1 * bv.y;
        P0 *= a.x;        P1 *= a.y;
        if (fmaxf(fabsf(P0), fabsf(P1)) < 1e-30f) break;
    }

    float dv[4], uv[4]; float4 bc[4];
    #pragma unroll
    for (int q = 0; q < 4; ++q) {
        dv[q] = dl[(size_t)q * DI]; uv[q] = ul[(size_t)q * DI]; bc[q] = bcl[(size_t)q * 8];
    }
    for (int j = 0; j < LCHUNK; j += 4) {
        float nd[4], nu[4]; float4 nbc[4];
        if (j + 4 < LCHUNK) {
            #pragma unroll
            for (int q = 0; q < 4; ++q) {
                int jj = j + 4 + q;
                nd[q] = dl[(size_t)jj * DI]; nu[q] = ul[(size_t)jj * DI]; nbc[q] = bcl[(size_t)jj * 8];
            }
        }
        #pragma unroll
        for (int q = 0; q < 4; ++q) {
            float e0 = __expf(dv[q] * Av0);
            float e1 = __expf(dv[q] * Av1);
            float du = dv[q] * uv[q];
            h0 = e0 * h0 + bc[q].x * du;
            h1 = e1 * h1 + bc[q].y * du;
            float acc = h0 * bc[q].z + h1 * bc[q].w;
            acc += __shfl_xor(acc, 4, 8);
            acc += __shfl_xor(acc, 2, 8);
            acc += __shfl_xor(acc, 1, 8);
            if (p == 0) yl[(size_t)(j + q) * DI] = acc + uv[q] * Dv;
        }
        #pragma unroll
        for (int q = 0; q < 4; ++q) { dv[q]=nd[q]; uv[q]=nu[q]; bc[q]=nbc[q]; }
    }
}

// ---------------------------------------------------------------------------
// LayerNorm over d (384) + affine + z-mul (z in bf16); unpermute folded into
// write; yn out in bf16.
// ---------------------------------------------------------------------------
__global__ __launch_bounds__(128) void ln_mul(
    const float* __restrict__ yt, const unsigned short* __restrict__ z,
    const int* __restrict__ scan_path,
    const float* __restrict__ ln_w, const float* __restrict__ ln_b,
    unsigned short* __restrict__ yn)
{
    const int j = blockIdx.x;
    const int b = blockIdx.y;
    const int l = scan_path[j];
    const int t = threadIdx.x;
    const float* row = yt + ((size_t)(b * LL + j)) * DI;
    float v0 = row[t], v1 = row[t + 128], v2 = row[t + 256];
    float s  = v0 + v1 + v2;
    float s2 = v0*v0 + v1*v1 + v2*v2;
    #pragma unroll
    for (int off = 32; off > 0; off >>= 1) {
        s  += __shfl_down(s, off);
        s2 += __shfl_down(s2, off);
    }
    __shared__ float red[4];
    if ((t & 63) == 0) { red[(t >> 6) * 2] = s; red[(t >> 6) * 2 + 1] = s2; }
    __syncthreads();
    float S  = red[0] + red[2];
    float S2 = red[1] + red[3];
    float mu  = S * (1.0f / DI);
    float var = S2 * (1.0f / DI) - mu * mu;
    float inv = rsqrtf(var + 1e-5f);

    const unsigned short* zr = z + ((size_t)(b * LL + l)) * DI;
    unsigned short* o = yn + ((size_t)(b * LL + l)) * DI;
    o[t]       = f2bf(((v0 - mu) * inv * ln_w[t]       + ln_b[t])       * bf2f(zr[t]));
    o[t + 128] = f2bf(((v1 - mu) * inv * ln_w[t + 128] + ln_b[t + 128]) * bf2f(zr[t + 128]));
    o[t + 256] = f2bf(((v2 - mu) * inv * ln_w[t + 256] + ln_b[t + 256]) * bf2f(zr[t + 256]));
}

// ---------------------------------------------------------------------------
extern "C" void kernel_launch(void* const* d_in, const int* in_sizes, int n_in,
                              void* d_out, int out_size, void* d_ws, size_t ws_size,
                              hipStream_t stream) {
    const float* x          = (const float*)d_in[0];
    const float* cond       = (const float*)d_in[1];
    const float* W_in       = (const float*)d_in[2];
    const float* W_con      = (const float*)d_in[3];
    const float* conv_w     = (const float*)d_in[4];
    const float* conv_b     = (const float*)d_in[5];
    const float* con_conv_w = (const float*)d_in[6];
    const float* con_conv_b = (const float*)d_in[7];
    const float* x_proj_w   = (const float*)d_in[8];
    const float* dt_proj_w  = (const float*)d_in[9];
    const float* dt_proj_b  = (const float*)d_in[10];
    const float* A_logs     = (const float*)d_in[11];
    const float* Ds         = (const float*)d_in[12];
    const float* ln_w       = (const float*)d_in[13];
    const float* ln_b       = (const float*)d_in[14];
    const float* W_out      = (const float*)d_in[15];
    const int*   scan_path  = (const int*)d_in[16];
    const int*   rev_path   = (const int*)d_in[17];

    float* ws = (float*)d_ws;
    const size_t S  = (size_t)BB * LL * DI;            // 3,145,728 floats
    const size_t SC = (size_t)NCHUNK * BB * DI * NS;   // 1,572,864 floats
    float* yt      = ws + 0 * S;
    float* zslab   = ws + 1 * S;                       // z_bf (ushort, half used)
    float* ynslab  = ws + 2 * S;                       // yn_bf (ushort, half used)
    float* xs_buf  = ws + 3 * S;
    float* dl_buf  = ws + 4 * S;
    float* btct    = ws + 5 * S;                       // BB*LL*32 floats, packed
    float* chunkA  = btct + (size_t)BB * LL * 32;
    float* chunkB  = chunkA + SC;
    float* bfpool  = chunkB + SC;                      // bf16 staging area

    unsigned short* z_bf     = (unsigned short*)zslab;             // ROWS*DI
    unsigned short* yn_bf    = (unsigned short*)ynslab;            // ROWS*DI
    unsigned short* s_bf     = (unsigned short*)bfpool;            // ROWS*DI
    unsigned short* xa_bf    = s_bf + (size_t)ROWS * DI;           // ROWS*DI
    unsigned short* c_bf     = xa_bf + (size_t)ROWS * DI;          // ROWS*DI
    unsigned short* w_in_bf  = c_bf + (size_t)ROWS * DI;           // 768*192
    unsigned short* w_con_bf = w_in_bf + 768 * DM;                 // 384*192
    unsigned short* w_out_bf = w_con_bf + 384 * DM;                // 192*384
    unsigned short* wcomb_bf = w_out_bf + 192 * DI;                // 448*384

    // 0) weight prep (casts + combined weight), one launch
    prep_weights<<<(73728 + NCOMB * DI + 255) / 256, 256, 0, stream>>>(
        W_in, W_con, W_out, x_proj_w, dt_proj_w,
        w_in_bf, w_con_bf, w_out_bf, wcomb_bf);

    // 1+2) dual GEMM: xz = x @ W_in.T (xa,z -> bf16) AND c = cond @ W_con.T (bf16)
    gemm_dual<<<dim3(ROWS / 64, 12, 2), 256, 0, stream>>>(
        x, cond, w_in_bf, w_con_bf, xa_bf, z_bf, c_bf);
    // 3) fused depthwise convs (bf16 in) + silu + scatter to scan order
    dwconv2_scatter<<<dim3(64, 12, BB), 256, 0, stream>>>(
        xa_bf, c_bf, conv_w, conv_b, con_conv_w, con_conv_b,
        rev_path, xs_buf, s_bf);
    // 4) combined GEMM: delta (softplus) + packed btct
    gemm_bf16<<<dim3(ROWS / 64, NCOMB / 64), 256, 0, stream>>>(
        s_bf, wcomb_bf, dt_proj_b, dl_buf, (void*)btct, ROWS, NCOMB, DI, 2);
    // 5) chunked parallel scan: pass A, then pass C with coalesced inline fold
    scan_chunkA<<<dim3(NCHUNK, DI / 32, BB), 256, 0, stream>>>(
        xs_buf, dl_buf, btct, A_logs, chunkA, chunkB);
    scan_chunkC<<<dim3(NCHUNK, DI / 32, BB), 256, 0, stream>>>(
        xs_buf, dl_buf, btct, A_logs, Ds, chunkA, chunkB, yt);
    // 6) LN + z-mul (unpermute folded in), yn in bf16
    ln_mul<<<dim3(LL, BB), 128, 0, stream>>>(yt, z_bf, scan_path, ln_w, ln_b, yn_bf);
    // 7) out = yn @ W_out.T
    gemm_bf16<<<dim3(ROWS / 64, 192 / 64), 256, 0, stream>>>(
        yn_bf, w_out_bf, nullptr, (float*)d_out, nullptr, ROWS, DM, DI, 1);
}

// Round 17
// 206.331 us; speedup vs baseline: 1.0329x; 1.0006x over previous
//
#include <hip/hip_runtime.h>
#include <math.h>

// Problem constants
#define BB 2
#define HH 64
#define WW 64
#define DM 192
#define DI 384
#define NS 16
#define DTR 12
#define LL 4096
#define ROWS (BB*LL)   // 8192
#define NCHUNK 128
#define LCHUNK 32      // NCHUNK*LCHUNK == LL
#define NCOMB 448      // padded combined-weight rows (416 real)
#define CSTRIDE ((size_t)BB * DI * 8)   // float2 elems per chunk slab

typedef __attribute__((ext_vector_type(8))) short bf16x8;
typedef __attribute__((ext_vector_type(4))) float f32x4;

__device__ __forceinline__ float silu_f(float v) {
    return v / (1.0f + __expf(-v));
}

// fp32 -> bf16 (RNE) bit trick
__device__ __forceinline__ unsigned short f2bf(float f) {
    union { float f; unsigned int u; } c; c.f = f;
    unsigned int u = c.u;
    u += 0x7fffu + ((u >> 16) & 1u);
    return (unsigned short)(u >> 16);
}
__device__ __forceinline__ float bf2f(unsigned short h) {
    union { unsigned int u; float f; } c; c.u = ((unsigned int)h) << 16;
    return c.f;
}

__device__ __forceinline__ bf16x8 f2bf8(float4 a, float4 b) {
    bf16x8 r;
    r[0] = (short)f2bf(a.x); r[1] = (short)f2bf(a.y);
    r[2] = (short)f2bf(a.z); r[3] = (short)f2bf(a.w);
    r[4] = (short)f2bf(b.x); r[5] = (short)f2bf(b.y);
    r[6] = (short)f2bf(b.z); r[7] = (short)f2bf(b.w);
    return r;
}

// ---------------------------------------------------------------------------
// One prep kernel: cast W_in/W_con/W_out to bf16 AND build combined weight
// Wc[448][384] (rows 0..383 = dt_w @ x_proj_w[:12], 384..415 = B/C rows).
// ---------------------------------------------------------------------------
__global__ __launch_bounds__(256) void prep_weights(
    const float* __restrict__ w_in, const float* __restrict__ w_con,
    const float* __restrict__ w_out,
    const float* __restrict__ x_proj_w, const float* __restrict__ dt_w,
    unsigned short* __restrict__ w_in_bf, unsigned short* __restrict__ w_con_bf,
    unsigned short* __restrict__ w_out_bf, unsigned short* __restrict__ wc)
{
    int idx = blockIdx.x * 256 + threadIdx.x;
    if (idx < 73728) {
        const float4* src; ushort4* dst; int off;
        if (idx < 36864)      { src = (const float4*)w_in;  dst = (ushort4*)w_in_bf;  off = idx; }
        else if (idx < 55296) { src = (const float4*)w_con; dst = (ushort4*)w_con_bf; off = idx - 36864; }
        else                  { src = (const float4*)w_out; dst = (ushort4*)w_out_bf; off = idx - 55296; }
        float4 v = src[off];
        ushort4 o;
        o.x = f2bf(v.x); o.y = f2bf(v.y); o.z = f2bf(v.z); o.w = f2bf(v.w);
        dst[off] = o;
    } else {
        int e = idx - 73728;                      // < 448*384
        if (e >= NCOMB * DI) return;
        int row = e / DI, k = e - row * DI;
        float v = 0.f;
        if (row < 384) {
            const float* dw = dt_w + row * DTR;
            #pragma unroll
            for (int r = 0; r < DTR; ++r) v += dw[r] * x_proj_w[r * DI + k];
        } else if (row < 416) {
            v = x_proj_w[(12 + (row - 384)) * DI + k];
        }
        wc[e] = f2bf(v);
    }
}

// ---------------------------------------------------------------------------
// Shared epilogue semantics (gemm_bf16 only):
// mode 1: plain ((float*)out0)[row*N+col]
// mode 2: col<384 -> out0 = softplus(v+bias[col]);
//         col in [384,400): B_n -> ((float*)out1)[row*32 + (n&7)*4 + (n>>3)]
//         col in [400,416): C_n -> ((float*)out1)[row*32 + (n&7)*4 + 2 + (n>>3)]
// ---------------------------------------------------------------------------
__device__ __forceinline__ void gemm_epilogue(
    int mode, int row, int col, int N, float v,
    const float* __restrict__ bias,
    float* __restrict__ out0, void* __restrict__ out1)
{
    if (mode == 1) {
        out0[(size_t)row * N + col] = v;
    } else {
        if (col < 384) {
            float a = v + bias[col];
            out0[(size_t)row * 384 + col] = (a > 20.f) ? a : log1pf(__expf(a));
        } else if (col < 416) {
            int idx = col - 384;
            int pos = (idx < 16) ? ((idx & 7) * 4 + (idx >> 3))
                                 : (((idx - 16) & 7) * 4 + 2 + ((idx - 16) >> 3));
            ((float*)out1)[(size_t)row * 32 + pos] = v;
        }
    }
}

// ---------------------------------------------------------------------------
// bf16 MFMA GEMM, 64x64 tile, BK=32, 256 threads. A is bf16.
// ---------------------------------------------------------------------------
__global__ __launch_bounds__(256) void gemm_bf16(
    const unsigned short* __restrict__ A, const unsigned short* __restrict__ W,
    const float* __restrict__ bias,
    float* __restrict__ out0, void* __restrict__ out1,
    int M, int N, int K, int mode)
{
    __shared__ __align__(16) unsigned short sA[64 * 40];
    __shared__ __align__(16) unsigned short sB[64 * 40];
    const int bm = blockIdx.x * 64;
    const int bn = blockIdx.y * 64;
    const int tid  = threadIdx.x;
    const int wave = tid >> 6;
    const int lane = tid & 63;
    const int quad = lane >> 4;
    const int l16  = lane & 15;
    const int lrow = tid >> 2;
    const int lkof = (tid & 3) * 8;

    f32x4 acc[4];
    #pragma unroll
    for (int t = 0; t < 4; ++t) acc[t] = (f32x4)(0.f);

    const int arow = (wave * 16 + l16) * 40 + quad * 8;

    for (int k0 = 0; k0 < K; k0 += 32) {
        *(bf16x8*)&sA[lrow * 40 + lkof] =
            *(const bf16x8*)&A[(size_t)(bm + lrow) * K + k0 + lkof];
        *(bf16x8*)&sB[lrow * 40 + lkof] =
            *(const bf16x8*)&W[(size_t)(bn + lrow) * K + k0 + lkof];
        __syncthreads();
        bf16x8 a = *(bf16x8*)&sA[arow];
        #pragma unroll
        for (int t = 0; t < 4; ++t) {
            bf16x8 b = *(bf16x8*)&sB[(t * 16 + l16) * 40 + quad * 8];
            acc[t] = __builtin_amdgcn_mfma_f32_16x16x32_bf16(a, b, acc[t], 0, 0, 0);
        }
        __syncthreads();
    }

    #pragma unroll
    for (int t = 0; t < 4; ++t) {
        int col = bn + t * 16 + l16;
        #pragma unroll
        for (int r = 0; r < 4; ++r) {
            int row = bm + wave * 16 + quad * 4 + r;
            gemm_epilogue(mode, row, col, N, acc[t][r], bias, out0, out1);
        }
    }
}

// ---------------------------------------------------------------------------
// Dual GEMM, BK=32: z=0 -> xz = x @ W_in.T (xa->bf16, z->bf16 silu, N=768);
// z=1 -> c = cond @ W_con.T (c->bf16, N=384). fp32 A cast during staging.
// ---------------------------------------------------------------------------
__global__ __launch_bounds__(256) void gemm_dual(
    const float* __restrict__ x, const float* __restrict__ cond,
    const unsigned short* __restrict__ w_in_bf,
    const unsigned short* __restrict__ w_con_bf,
    unsigned short* __restrict__ xa_bf, unsigned short* __restrict__ z_bf,
    unsigned short* __restrict__ c_bf)
{
    const int zz = blockIdx.z;
    if (zz == 1 && blockIdx.y >= 6) return;
    const float* A = zz ? cond : x;
    const unsigned short* W = zz ? w_con_bf : w_in_bf;

    __shared__ __align__(16) unsigned short sA[64 * 40];
    __shared__ __align__(16) unsigned short sB[64 * 40];
    const int bm = blockIdx.x * 64;
    const int bn = blockIdx.y * 64;
    const int tid  = threadIdx.x;
    const int wave = tid >> 6;
    const int lane = tid & 63;
    const int quad = lane >> 4;
    const int l16  = lane & 15;
    const int lrow = tid >> 2;
    const int lkof = (tid & 3) * 8;

    f32x4 acc[4];
    #pragma unroll
    for (int t = 0; t < 4; ++t) acc[t] = (f32x4)(0.f);

    const int arow = (wave * 16 + l16) * 40 + quad * 8;

    for (int k0 = 0; k0 < DM; k0 += 32) {
        const float* ap = &A[(size_t)(bm + lrow) * DM + k0 + lkof];
        float4 a0 = *(const float4*)ap;
        float4 a1 = *(const float4*)(ap + 4);
        *(bf16x8*)&sA[lrow * 40 + lkof] = f2bf8(a0, a1);
        *(bf16x8*)&sB[lrow * 40 + lkof] =
            *(const bf16x8*)&W[(size_t)(bn + lrow) * DM + k0 + lkof];
        __syncthreads();
        bf16x8 a = *(bf16x8*)&sA[arow];
        #pragma unroll
        for (int t = 0; t < 4; ++t) {
            bf16x8 b = *(bf16x8*)&sB[(t * 16 + l16) * 40 + quad * 8];
            acc[t] = __builtin_amdgcn_mfma_f32_16x16x32_bf16(a, b, acc[t], 0, 0, 0);
        }
        __syncthreads();
    }

    #pragma unroll
    for (int t = 0; t < 4; ++t) {
        int col = bn + t * 16 + l16;
        #pragma unroll
        for (int r = 0; r < 4; ++r) {
            int row = bm + wave * 16 + quad * 4 + r;
            float v = acc[t][r];
            if (zz == 0) {
                if (col < 384) xa_bf[(size_t)row * 384 + col] = f2bf(v);
                else           z_bf[(size_t)row * 384 + (col - 384)] = f2bf(silu_f(v));
            } else {
                c_bf[(size_t)row * 384 + col] = f2bf(v);
            }
        }
    }
}

// ---------------------------------------------------------------------------
// Fused depthwise 3x3 convs + bias + silu; inputs bf16, math fp32; writes
// xs (bf16) and s = silu(conv_x)+silu(conv_c) (bf16), SCATTERED to scan
// order. 32-channel groups; grid (64, 12, B).
// ---------------------------------------------------------------------------
__global__ __launch_bounds__(256) void dwconv2_scatter(
    const unsigned short* __restrict__ xin, const unsigned short* __restrict__ cin,
    const float* __restrict__ wx, const float* __restrict__ bx,
    const float* __restrict__ wc, const float* __restrict__ bc,
    const int* __restrict__ rev_scan_path,
    unsigned short* __restrict__ xs_bf, unsigned short* __restrict__ s_bf)
{
    const int tile = blockIdx.x;
    const int c0   = blockIdx.y * 32;
    const int b    = blockIdx.z;
    const int h0 = (tile >> 3) * 8, w0 = (tile & 7) * 8;
    __shared__ float smx[10 * 10 * 32];
    __shared__ float smc[10 * 10 * 32];
    __shared__ int   jtile[64];

    for (int idx = threadIdx.x; idx < 3200; idx += 256) {
        int pix = idx >> 5, ch = idx & 31;
        int py = pix / 10, px = pix - py * 10;
        int gh = h0 + py - 1, gw = w0 + px - 1;
        float vx = 0.f, vc = 0.f;
        if (gh >= 0 && gh < 64 && gw >= 0 && gw < 64) {
            size_t g = ((size_t)(b * LL + gh * 64 + gw)) * DI + c0 + ch;
            vx = bf2f(xin[g]); vc = bf2f(cin[g]);
        }
        smx[idx] = vx; smc[idx] = vc;
    }
    if (threadIdx.x < 64) {
        int l = (h0 + (threadIdx.x >> 3)) * 64 + (w0 + (threadIdx.x & 7));
        jtile[threadIdx.x] = rev_scan_path[l];
    }
    __syncthreads();

    const int ch = threadIdx.x & 31;
    const int pq = threadIdx.x >> 5;   // 0..7
    float wrx[9], wrc[9];
    #pragma unroll
    for (int k = 0; k < 9; ++k) {
        wrx[k] = wx[(c0 + ch) * 9 + k];
        wrc[k] = wc[(c0 + ch) * 9 + k];
    }
    const float bvx = bx[c0 + ch];
    const float bvc = bc[c0 + ch];

    #pragma unroll
    for (int i = 0; i < 8; ++i) {
        int p  = pq * 8 + i;           // 0..63
        int ph = p >> 3, pw = p & 7;
        float ax = bvx, ac = bvc;
        #pragma unroll
        for (int ki = 0; ki < 3; ++ki)
            #pragma unroll
            for (int kj = 0; kj < 3; ++kj) {
                int si = ((ph + ki) * 10 + (pw + kj)) * 32 + ch;
                ax += wrx[ki * 3 + kj] * smx[si];
                ac += wrc[ki * 3 + kj] * smc[si];
            }
        float xv = silu_f(ax);
        float sv = xv + silu_f(ac);
        size_t o = ((size_t)(b * LL + jtile[p])) * DI + c0 + ch;
        xs_bf[o] = f2bf(xv);
        s_bf[o]  = f2bf(sv);
    }
}

// ---------------------------------------------------------------------------
// Pass A: per-chunk composite, register-prefetch. xs in bf16.
// 8 lanes/channel, 2 states/lane. grid (NCHUNK, DI/32, BB). Composite
// layout CHUNK-MAJOR. Chunk decay = exp(Av * sum(delta)).
// ---------------------------------------------------------------------------
__global__ __launch_bounds__(256) void scan_chunkA(
    const unsigned short* __restrict__ xs, const float* __restrict__ delta,
    const float* __restrict__ btct, const float* __restrict__ A_logs,
    float* __restrict__ chunkA, float* __restrict__ chunkB)
{
    const int c = blockIdx.x;
    const int g = blockIdx.y;
    const int b = blockIdx.z;
    const int t = threadIdx.x;
    const int grp = t >> 3, p = t & 7;
    const int d = g * 32 + grp;
    const float Av0 = -__expf(A_logs[d * NS + p]);
    const float Av1 = -__expf(A_logs[d * NS + p + 8]);
    const int j0 = c * LCHUNK;

    const float*          dl = delta + ((size_t)b * LL + j0) * DI + d;
    const unsigned short* ul = xs    + ((size_t)b * LL + j0) * DI + d;
    const float2*         bl = (const float2*)btct + ((size_t)b * LL + j0) * 16 + p * 2;

    float h0 = 0.f, h1 = 0.f, Sd = 0.f;
    float dv[4], uv[4]; float2 bv[4];
    #pragma unroll
    for (int q = 0; q < 4; ++q) {
        dv[q] = dl[(size_t)q * DI]; uv[q] = bf2f(ul[(size_t)q * DI]); bv[q] = bl[(size_t)q * 16];
    }
    for (int j = 0; j < LCHUNK; j += 4) {
        float nd[4], nu[4]; float2 nb[4];
        if (j + 4 < LCHUNK) {
            #pragma unroll
            for (int q = 0; q < 4; ++q) {
                int jj = j + 4 + q;
                nd[q] = dl[(size_t)jj * DI]; nu[q] = bf2f(ul[(size_t)jj * DI]); nb[q] = bl[(size_t)jj * 16];
            }
        }
        #pragma unroll
        for (int q = 0; q < 4; ++q) {
            float e0 = __expf(dv[q] * Av0);
            float e1 = __expf(dv[q] * Av1);
            float du = dv[q] * uv[q];
            h0 = e0 * h0 + bv[q].x * du;
            h1 = e1 * h1 + bv[q].y * du;
            Sd += dv[q];
        }
        #pragma unroll
        for (int q = 0; q < 4; ++q) { dv[q]=nd[q]; uv[q]=nu[q]; bv[q]=nb[q]; }
    }
    size_t idx = (size_t)c * CSTRIDE + ((size_t)b * DI + d) * 8 + p;
    ((float2*)chunkA)[idx] = make_float2(__expf(Sd * Av0), __expf(Sd * Av1));
    ((float2*)chunkB)[idx] = make_float2(h0, h1);
}

// ---------------------------------------------------------------------------
// Pass C: local scan seeded by an INLINE backward fold over the chunk-major
// composites (coalesced, early exit on underflow). xs in bf16; y out bf16.
// ---------------------------------------------------------------------------
__global__ __launch_bounds__(256) void scan_chunkC(
    const unsigned short* __restrict__ xs, const float* __restrict__ delta,
    const float* __restrict__ btct,
    const float* __restrict__ A_logs, const float* __restrict__ Ds,
    const float* __restrict__ chunkA, const float* __restrict__ chunkB,
    unsigned short* __restrict__ yt)
{
    const int c = blockIdx.x;
    const int g = blockIdx.y;
    const int b = blockIdx.z;
    const int t = threadIdx.x;
    const int grp = t >> 3, p = t & 7;
    const int d = g * 32 + grp;
    const float Av0 = -__expf(A_logs[d * NS + p]);
    const float Av1 = -__expf(A_logs[d * NS + p + 8]);
    const float Dv = Ds[d];
    const int j0 = c * LCHUNK;

    const float*          dl  = delta + ((size_t)b * LL + j0) * DI + d;
    const unsigned short* ul  = xs    + ((size_t)b * LL + j0) * DI + d;
    const float4*         bcl = (const float4*)btct + ((size_t)b * LL + j0) * 8 + p;
    unsigned short* yl = yt + ((size_t)b * LL + j0) * DI + d;

    const size_t off = ((size_t)b * DI + d) * 8 + p;
    const float2* A2 = (const float2*)chunkA;
    const float2* B2 = (const float2*)chunkB;
    float h0 = 0.f, h1 = 0.f, P0 = 1.f, P1 = 1.f;
    for (int i = c - 1; i >= 0; --i) {
        size_t ix = (size_t)i * CSTRIDE + off;
        float2 a = A2[ix], bv = B2[ix];
        h0 += P0 * bv.x;  h1 += P1 * bv.y;
        P0 *= a.x;        P1 *= a.y;
        if (fmaxf(fabsf(P0), fabsf(P1)) < 1e-30f) break;
    }

    float dv[4], uv[4]; float4 bc[4];
    #pragma unroll
    for (int q = 0; q < 4; ++q) {
        dv[q] = dl[(size_t)q * DI]; uv[q] = bf2f(ul[(size_t)q * DI]); bc[q] = bcl[(size_t)q * 8];
    }
    for (int j = 0; j < LCHUNK; j += 4) {
        float nd[4], nu[4]; float4 nbc[4];
        if (j + 4 < LCHUNK) {
            #pragma unroll
            for (int q = 0; q < 4; ++q) {
                int jj = j + 4 + q;
                nd[q] = dl[(size_t)jj * DI]; nu[q] = bf2f(ul[(size_t)jj * DI]); nbc[q] = bcl[(size_t)jj * 8];
            }
        }
        #pragma unroll
        for (int q = 0; q < 4; ++q) {
            float e0 = __expf(dv[q] * Av0);
            float e1 = __expf(dv[q] * Av1);
            float du = dv[q] * uv[q];
            h0 = e0 * h0 + bc[q].x * du;
            h1 = e1 * h1 + bc[q].y * du;
            float acc = h0 * bc[q].z + h1 * bc[q].w;
            acc += __shfl_xor(acc, 4, 8);
            acc += __shfl_xor(acc, 2, 8);
            acc += __shfl_xor(acc, 1, 8);
            if (p == 0) yl[(size_t)(j + q) * DI] = f2bf(acc + uv[q] * Dv);
        }
        #pragma unroll
        for (int q = 0; q < 4; ++q) { dv[q]=nd[q]; uv[q]=nu[q]; bc[q]=nbc[q]; }
    }
}

// ---------------------------------------------------------------------------
// LayerNorm over d (384) + affine + z-mul (yt and z in bf16); unpermute
// folded into write; yn out in bf16.
// ---------------------------------------------------------------------------
__global__ __launch_bounds__(128) void ln_mul(
    const unsigned short* __restrict__ yt, const unsigned short* __restrict__ z,
    const int* __restrict__ scan_path,
    const float* __restrict__ ln_w, const float* __restrict__ ln_b,
    unsigned short* __restrict__ yn)
{
    const int j = blockIdx.x;
    const int b = blockIdx.y;
    const int l = scan_path[j];
    const int t = threadIdx.x;
    const unsigned short* row = yt + ((size_t)(b * LL + j)) * DI;
    float v0 = bf2f(row[t]), v1 = bf2f(row[t + 128]), v2 = bf2f(row[t + 256]);
    float s  = v0 + v1 + v2;
    float s2 = v0*v0 + v1*v1 + v2*v2;
    #pragma unroll
    for (int off = 32; off > 0; off >>= 1) {
        s  += __shfl_down(s, off);
        s2 += __shfl_down(s2, off);
    }
    __shared__ float red[4];
    if ((t & 63) == 0) { red[(t >> 6) * 2] = s; red[(t >> 6) * 2 + 1] = s2; }
    __syncthreads();
    float S  = red[0] + red[2];
    float S2 = red[1] + red[3];
    float mu  = S * (1.0f / DI);
    float var = S2 * (1.0f / DI) - mu * mu;
    float inv = rsqrtf(var + 1e-5f);

    const unsigned short* zr = z + ((size_t)(b * LL + l)) * DI;
    unsigned short* o = yn + ((size_t)(b * LL + l)) * DI;
    o[t]       = f2bf(((v0 - mu) * inv * ln_w[t]       + ln_b[t])       * bf2f(zr[t]));
    o[t + 128] = f2bf(((v1 - mu) * inv * ln_w[t + 128] + ln_b[t + 128]) * bf2f(zr[t + 128]));
    o[t + 256] = f2bf(((v2 - mu) * inv * ln_w[t + 256] + ln_b[t + 256]) * bf2f(zr[t + 256]));
}

// ---------------------------------------------------------------------------
extern "C" void kernel_launch(void* const* d_in, const int* in_sizes, int n_in,
                              void* d_out, int out_size, void* d_ws, size_t ws_size,
                              hipStream_t stream) {
    const float* x          = (const float*)d_in[0];
    const float* cond       = (const float*)d_in[1];
    const float* W_in       = (const float*)d_in[2];
    const float* W_con      = (const float*)d_in[3];
    const float* conv_w     = (const float*)d_in[4];
    const float* conv_b     = (const float*)d_in[5];
    const float* con_conv_w = (const float*)d_in[6];
    const float* con_conv_b = (const float*)d_in[7];
    const float* x_proj_w   = (const float*)d_in[8];
    const float* dt_proj_w  = (const float*)d_in[9];
    const float* dt_proj_b  = (const float*)d_in[10];
    const float* A_logs     = (const float*)d_in[11];
    const float* Ds         = (const float*)d_in[12];
    const float* ln_w       = (const float*)d_in[13];
    const float* ln_b       = (const float*)d_in[14];
    const float* W_out      = (const float*)d_in[15];
    const int*   scan_path  = (const int*)d_in[16];
    const int*   rev_path   = (const int*)d_in[17];

    float* ws = (float*)d_ws;
    const size_t S  = (size_t)BB * LL * DI;            // 3,145,728 floats
    const size_t SC = (size_t)NCHUNK * BB * DI * NS;   // 1,572,864 floats
    float* ytslab  = ws + 0 * S;                       // yt_bf (ushort, half used)
    float* zslab   = ws + 1 * S;                       // z_bf (ushort, half used)
    float* ynslab  = ws + 2 * S;                       // yn_bf (ushort, half used)
    float* xsslab  = ws + 3 * S;                       // xs_bf (ushort, half used)
    float* dl_buf  = ws + 4 * S;
    float* btct    = ws + 5 * S;                       // BB*LL*32 floats, packed
    float* chunkA  = btct + (size_t)BB * LL * 32;
    float* chunkB  = chunkA + SC;
    float* bfpool  = chunkB + SC;                      // bf16 staging area

    unsigned short* yt_bf    = (unsigned short*)ytslab;            // ROWS*DI
    unsigned short* z_bf     = (unsigned short*)zslab;             // ROWS*DI
    unsigned short* yn_bf    = (unsigned short*)ynslab;            // ROWS*DI
    unsigned short* xs_bf    = (unsigned short*)xsslab;            // ROWS*DI
    unsigned short* s_bf     = (unsigned short*)bfpool;            // ROWS*DI
    unsigned short* xa_bf    = s_bf + (size_t)ROWS * DI;           // ROWS*DI
    unsigned short* c_bf     = xa_bf + (size_t)ROWS * DI;          // ROWS*DI
    unsigned short* w_in_bf  = c_bf + (size_t)ROWS * DI;           // 768*192
    unsigned short* w_con_bf = w_in_bf + 768 * DM;                 // 384*192
    unsigned short* w_out_bf = w_con_bf + 384 * DM;                // 192*384
    unsigned short* wcomb_bf = w_out_bf + 192 * DI;                // 448*384

    // 0) weight prep (casts + combined weight), one launch
    prep_weights<<<(73728 + NCOMB * DI + 255) / 256, 256, 0, stream>>>(
        W_in, W_con, W_out, x_proj_w, dt_proj_w,
        w_in_bf, w_con_bf, w_out_bf, wcomb_bf);

    // 1+2) dual GEMM: xz = x @ W_in.T (xa,z -> bf16) AND c = cond @ W_con.T (bf16)
    gemm_dual<<<dim3(ROWS / 64, 12, 2), 256, 0, stream>>>(
        x, cond, w_in_bf, w_con_bf, xa_bf, z_bf, c_bf);
    // 3) fused depthwise convs (bf16 in/out) + silu + scatter to scan order
    dwconv2_scatter<<<dim3(64, 12, BB), 256, 0, stream>>>(
        xa_bf, c_bf, conv_w, conv_b, con_conv_w, con_conv_b,
        rev_path, xs_bf, s_bf);
    // 4) combined GEMM: delta (softplus) + packed btct
    gemm_bf16<<<dim3(ROWS / 64, NCOMB / 64), 256, 0, stream>>>(
        s_bf, wcomb_bf, dt_proj_b, dl_buf, (void*)btct, ROWS, NCOMB, DI, 2);
    // 5) chunked parallel scan: pass A, then pass C with coalesced inline fold
    scan_chunkA<<<dim3(NCHUNK, DI / 32, BB), 256, 0, stream>>>(
        xs_bf, dl_buf, btct, A_logs, chunkA, chunkB);
    scan_chunkC<<<dim3(NCHUNK, DI / 32, BB), 256, 0, stream>>>(
        xs_bf, dl_buf, btct, A_logs, Ds, chunkA, chunkB, yt_bf);
    // 6) LN + z-mul (unpermute folded in), yn in bf16
    ln_mul<<<dim3(LL, BB), 128, 0, stream>>>(yt_bf, z_bf, scan_path, ln_w, ln_b, yn_bf);
    // 7) out = yn @ W_out.T
    gemm_bf16<<<dim3(ROWS / 64, 192 / 64), 256, 0, stream>>>(
        yn_bf, w_out_bf, nullptr, (float*)d_out, nullptr, ROWS, DM, DI, 1);
}

// Round 18
// 205.028 us; speedup vs baseline: 1.0395x; 1.0064x over previous
//
#include <hip/hip_runtime.h>
#include <math.h>

// Problem constants
#define BB 2
#define HH 64
#define WW 64
#define DM 192
#define DI 384
#define NS 16
#define DTR 12
#define LL 4096
#define ROWS (BB*LL)   // 8192
#define NCHUNK 128
#define LCHUNK 32      // NCHUNK*LCHUNK == LL
#define NCOMB 448      // padded combined-weight rows (416 real)
#define CSTRIDE ((size_t)BB * DI * 8)   // float2 elems per chunk slab

typedef __attribute__((ext_vector_type(8))) short bf16x8;
typedef __attribute__((ext_vector_type(4))) float f32x4;

__device__ __forceinline__ float silu_f(float v) {
    return v / (1.0f + __expf(-v));
}

// fp32 -> bf16 (RNE) bit trick
__device__ __forceinline__ unsigned short f2bf(float f) {
    union { float f; unsigned int u; } c; c.f = f;
    unsigned int u = c.u;
    u += 0x7fffu + ((u >> 16) & 1u);
    return (unsigned short)(u >> 16);
}
__device__ __forceinline__ float bf2f(unsigned short h) {
    union { unsigned int u; float f; } c; c.u = ((unsigned int)h) << 16;
    return c.f;
}

__device__ __forceinline__ bf16x8 f2bf8(float4 a, float4 b) {
    bf16x8 r;
    r[0] = (short)f2bf(a.x); r[1] = (short)f2bf(a.y);
    r[2] = (short)f2bf(a.z); r[3] = (short)f2bf(a.w);
    r[4] = (short)f2bf(b.x); r[5] = (short)f2bf(b.y);
    r[6] = (short)f2bf(b.z); r[7] = (short)f2bf(b.w);
    return r;
}

// ---------------------------------------------------------------------------
// One prep kernel: cast W_in/W_con/W_out to bf16 AND build combined weight
// Wc[448][384] (rows 0..383 = dt_w @ x_proj_w[:12], 384..415 = B/C rows).
// ---------------------------------------------------------------------------
__global__ __launch_bounds__(256) void prep_weights(
    const float* __restrict__ w_in, const float* __restrict__ w_con,
    const float* __restrict__ w_out,
    const float* __restrict__ x_proj_w, const float* __restrict__ dt_w,
    unsigned short* __restrict__ w_in_bf, unsigned short* __restrict__ w_con_bf,
    unsigned short* __restrict__ w_out_bf, unsigned short* __restrict__ wc)
{
    int idx = blockIdx.x * 256 + threadIdx.x;
    if (idx < 73728) {
        const float4* src; ushort4* dst; int off;
        if (idx < 36864)      { src = (const float4*)w_in;  dst = (ushort4*)w_in_bf;  off = idx; }
        else if (idx < 55296) { src = (const float4*)w_con; dst = (ushort4*)w_con_bf; off = idx - 36864; }
        else                  { src = (const float4*)w_out; dst = (ushort4*)w_out_bf; off = idx - 55296; }
        float4 v = src[off];
        ushort4 o;
        o.x = f2bf(v.x); o.y = f2bf(v.y); o.z = f2bf(v.z); o.w = f2bf(v.w);
        dst[off] = o;
    } else {
        int e = idx - 73728;                      // < 448*384
        if (e >= NCOMB * DI) return;
        int row = e / DI, k = e - row * DI;
        float v = 0.f;
        if (row < 384) {
            const float* dw = dt_w + row * DTR;
            #pragma unroll
            for (int r = 0; r < DTR; ++r) v += dw[r] * x_proj_w[r * DI + k];
        } else if (row < 416) {
            v = x_proj_w[(12 + (row - 384)) * DI + k];
        }
        wc[e] = f2bf(v);
    }
}

// ---------------------------------------------------------------------------
// bf16 MFMA GEMM, 64x64 tile, BK=32, 256 threads. A is bf16.
// mode 1: plain ((float*)out0)[row*N+col]
// mode 2: col<384 -> LOW ushort of du[row*384+col] = bf16(softplus(v+bias));
//         col in [384,400): B_n -> ((float*)out1)[row*32 + (n&7)*4 + (n>>3)]
//         col in [400,416): C_n -> ((float*)out1)[row*32 + (n&7)*4 + 2 + (n>>3)]
// ---------------------------------------------------------------------------
__global__ __launch_bounds__(256) void gemm_bf16(
    const unsigned short* __restrict__ A, const unsigned short* __restrict__ W,
    const float* __restrict__ bias,
    float* __restrict__ out0, void* __restrict__ out1,
    unsigned short* __restrict__ du_lo,    // mode 2 only: ushort* view of du
    int M, int N, int K, int mode)
{
    __shared__ __align__(16) unsigned short sA[64 * 40];
    __shared__ __align__(16) unsigned short sB[64 * 40];
    const int bm = blockIdx.x * 64;
    const int bn = blockIdx.y * 64;
    const int tid  = threadIdx.x;
    const int wave = tid >> 6;
    const int lane = tid & 63;
    const int quad = lane >> 4;
    const int l16  = lane & 15;
    const int lrow = tid >> 2;
    const int lkof = (tid & 3) * 8;

    f32x4 acc[4];
    #pragma unroll
    for (int t = 0; t < 4; ++t) acc[t] = (f32x4)(0.f);

    const int arow = (wave * 16 + l16) * 40 + quad * 8;

    for (int k0 = 0; k0 < K; k0 += 32) {
        *(bf16x8*)&sA[lrow * 40 + lkof] =
            *(const bf16x8*)&A[(size_t)(bm + lrow) * K + k0 + lkof];
        *(bf16x8*)&sB[lrow * 40 + lkof] =
            *(const bf16x8*)&W[(size_t)(bn + lrow) * K + k0 + lkof];
        __syncthreads();
        bf16x8 a = *(bf16x8*)&sA[arow];
        #pragma unroll
        for (int t = 0; t < 4; ++t) {
            bf16x8 b = *(bf16x8*)&sB[(t * 16 + l16) * 40 + quad * 8];
            acc[t] = __builtin_amdgcn_mfma_f32_16x16x32_bf16(a, b, acc[t], 0, 0, 0);
        }
        __syncthreads();
    }

    #pragma unroll
    for (int t = 0; t < 4; ++t) {
        int col = bn + t * 16 + l16;
        #pragma unroll
        for (int r = 0; r < 4; ++r) {
            int row = bm + wave * 16 + quad * 4 + r;
            float v = acc[t][r];
            if (mode == 1) {
                out0[(size_t)row * N + col] = v;
            } else {
                if (col < 384) {
                    float a = v + bias[col];
                    float sp = (a > 20.f) ? a : log1pf(__expf(a));
                    du_lo[((size_t)row * 384 + col) * 2] = f2bf(sp);
                } else if (col < 416) {
                    int idx = col - 384;
                    int pos = (idx < 16) ? ((idx & 7) * 4 + (idx >> 3))
                                         : (((idx - 16) & 7) * 4 + 2 + ((idx - 16) >> 3));
                    ((float*)out1)[(size_t)row * 32 + pos] = v;
                }
            }
        }
    }
}

// ---------------------------------------------------------------------------
// Dual GEMM, BK=32: z=0 -> xz = x @ W_in.T (xa->bf16, z->bf16 silu, N=768);
// z=1 -> c = cond @ W_con.T (c->bf16, N=384). fp32 A cast during staging.
// ---------------------------------------------------------------------------
__global__ __launch_bounds__(256) void gemm_dual(
    const float* __restrict__ x, const float* __restrict__ cond,
    const unsigned short* __restrict__ w_in_bf,
    const unsigned short* __restrict__ w_con_bf,
    unsigned short* __restrict__ xa_bf, unsigned short* __restrict__ z_bf,
    unsigned short* __restrict__ c_bf)
{
    const int zz = blockIdx.z;
    if (zz == 1 && blockIdx.y >= 6) return;
    const float* A = zz ? cond : x;
    const unsigned short* W = zz ? w_con_bf : w_in_bf;

    __shared__ __align__(16) unsigned short sA[64 * 40];
    __shared__ __align__(16) unsigned short sB[64 * 40];
    const int bm = blockIdx.x * 64;
    const int bn = blockIdx.y * 64;
    const int tid  = threadIdx.x;
    const int wave = tid >> 6;
    const int lane = tid & 63;
    const int quad = lane >> 4;
    const int l16  = lane & 15;
    const int lrow = tid >> 2;
    const int lkof = (tid & 3) * 8;

    f32x4 acc[4];
    #pragma unroll
    for (int t = 0; t < 4; ++t) acc[t] = (f32x4)(0.f);

    const int arow = (wave * 16 + l16) * 40 + quad * 8;

    for (int k0 = 0; k0 < DM; k0 += 32) {
        const float* ap = &A[(size_t)(bm + lrow) * DM + k0 + lkof];
        float4 a0 = *(const float4*)ap;
        float4 a1 = *(const float4*)(ap + 4);
        *(bf16x8*)&sA[lrow * 40 + lkof] = f2bf8(a0, a1);
        *(bf16x8*)&sB[lrow * 40 + lkof] =
            *(const bf16x8*)&W[(size_t)(bn + lrow) * DM + k0 + lkof];
        __syncthreads();
        bf16x8 a = *(bf16x8*)&sA[arow];
        #pragma unroll
        for (int t = 0; t < 4; ++t) {
            bf16x8 b = *(bf16x8*)&sB[(t * 16 + l16) * 40 + quad * 8];
            acc[t] = __builtin_amdgcn_mfma_f32_16x16x32_bf16(a, b, acc[t], 0, 0, 0);
        }
        __syncthreads();
    }

    #pragma unroll
    for (int t = 0; t < 4; ++t) {
        int col = bn + t * 16 + l16;
        #pragma unroll
        for (int r = 0; r < 4; ++r) {
            int row = bm + wave * 16 + quad * 4 + r;
            float v = acc[t][r];
            if (zz == 0) {
                if (col < 384) xa_bf[(size_t)row * 384 + col] = f2bf(v);
                else           z_bf[(size_t)row * 384 + (col - 384)] = f2bf(silu_f(v));
            } else {
                c_bf[(size_t)row * 384 + col] = f2bf(v);
            }
        }
    }
}

// ---------------------------------------------------------------------------
// Fused depthwise 3x3 convs + bias + silu; inputs bf16, math fp32; writes
// u = silu(conv_x) into the HIGH ushort of du[row][d], and s (bf16),
// SCATTERED to scan order. 32-channel groups; grid (64, 12, B).
// ---------------------------------------------------------------------------
__global__ __launch_bounds__(256) void dwconv2_scatter(
    const unsigned short* __restrict__ xin, const unsigned short* __restrict__ cin,
    const float* __restrict__ wx, const float* __restrict__ bx,
    const float* __restrict__ wc, const float* __restrict__ bc,
    const int* __restrict__ rev_scan_path,
    unsigned short* __restrict__ du_hi,   // ushort* view of du; write idx*2+1
    unsigned short* __restrict__ s_bf)
{
    const int tile = blockIdx.x;
    const int c0   = blockIdx.y * 32;
    const int b    = blockIdx.z;
    const int h0 = (tile >> 3) * 8, w0 = (tile & 7) * 8;
    __shared__ float smx[10 * 10 * 32];
    __shared__ float smc[10 * 10 * 32];
    __shared__ int   jtile[64];

    for (int idx = threadIdx.x; idx < 3200; idx += 256) {
        int pix = idx >> 5, ch = idx & 31;
        int py = pix / 10, px = pix - py * 10;
        int gh = h0 + py - 1, gw = w0 + px - 1;
        float vx = 0.f, vc = 0.f;
        if (gh >= 0 && gh < 64 && gw >= 0 && gw < 64) {
            size_t g = ((size_t)(b * LL + gh * 64 + gw)) * DI + c0 + ch;
            vx = bf2f(xin[g]); vc = bf2f(cin[g]);
        }
        smx[idx] = vx; smc[idx] = vc;
    }
    if (threadIdx.x < 64) {
        int l = (h0 + (threadIdx.x >> 3)) * 64 + (w0 + (threadIdx.x & 7));
        jtile[threadIdx.x] = rev_scan_path[l];
    }
    __syncthreads();

    const int ch = threadIdx.x & 31;
    const int pq = threadIdx.x >> 5;   // 0..7
    float wrx[9], wrc[9];
    #pragma unroll
    for (int k = 0; k < 9; ++k) {
        wrx[k] = wx[(c0 + ch) * 9 + k];
        wrc[k] = wc[(c0 + ch) * 9 + k];
    }
    const float bvx = bx[c0 + ch];
    const float bvc = bc[c0 + ch];

    #pragma unroll
    for (int i = 0; i < 8; ++i) {
        int p  = pq * 8 + i;           // 0..63
        int ph = p >> 3, pw = p & 7;
        float ax = bvx, ac = bvc;
        #pragma unroll
        for (int ki = 0; ki < 3; ++ki)
            #pragma unroll
            for (int kj = 0; kj < 3; ++kj) {
                int si = ((ph + ki) * 10 + (pw + kj)) * 32 + ch;
                ax += wrx[ki * 3 + kj] * smx[si];
                ac += wrc[ki * 3 + kj] * smc[si];
            }
        float xv = silu_f(ax);
        float sv = xv + silu_f(ac);
        size_t o = ((size_t)(b * LL + jtile[p])) * DI + c0 + ch;
        du_hi[o * 2 + 1] = f2bf(xv);
        s_bf[o]          = f2bf(sv);
    }
}

// ---------------------------------------------------------------------------
// Pass A: per-chunk composite, register-prefetch. (delta,u) packed in one
// uint stream -> 2 loads/step. grid (NCHUNK, DI/32, BB). Composite layout
// CHUNK-MAJOR. Chunk decay = exp(Av * sum(delta)).
// ---------------------------------------------------------------------------
__global__ __launch_bounds__(256) void scan_chunkA(
    const unsigned int* __restrict__ du, const float* __restrict__ btct,
    const float* __restrict__ A_logs,
    float* __restrict__ chunkA, float* __restrict__ chunkB)
{
    const int c = blockIdx.x;
    const int g = blockIdx.y;
    const int b = blockIdx.z;
    const int t = threadIdx.x;
    const int grp = t >> 3, p = t & 7;
    const int d = g * 32 + grp;
    const float Av0 = -__expf(A_logs[d * NS + p]);
    const float Av1 = -__expf(A_logs[d * NS + p + 8]);
    const int j0 = c * LCHUNK;

    const unsigned int* dul = du + ((size_t)b * LL + j0) * DI + d;
    const float2*       bl  = (const float2*)btct + ((size_t)b * LL + j0) * 16 + p * 2;

    float h0 = 0.f, h1 = 0.f, Sd = 0.f;
    unsigned int duv[4]; float2 bv[4];
    #pragma unroll
    for (int q = 0; q < 4; ++q) {
        duv[q] = dul[(size_t)q * DI]; bv[q] = bl[(size_t)q * 16];
    }
    for (int j = 0; j < LCHUNK; j += 4) {
        unsigned int ndu[4]; float2 nb[4];
        if (j + 4 < LCHUNK) {
            #pragma unroll
            for (int q = 0; q < 4; ++q) {
                int jj = j + 4 + q;
                ndu[q] = dul[(size_t)jj * DI]; nb[q] = bl[(size_t)jj * 16];
            }
        }
        #pragma unroll
        for (int q = 0; q < 4; ++q) {
            float dv = bf2f((unsigned short)(duv[q] & 0xffff));
            float uv = bf2f((unsigned short)(duv[q] >> 16));
            float e0 = __expf(dv * Av0);
            float e1 = __expf(dv * Av1);
            float duu = dv * uv;
            h0 = e0 * h0 + bv[q].x * duu;
            h1 = e1 * h1 + bv[q].y * duu;
            Sd += dv;
        }
        #pragma unroll
        for (int q = 0; q < 4; ++q) { duv[q]=ndu[q]; bv[q]=nb[q]; }
    }
    size_t idx = (size_t)c * CSTRIDE + ((size_t)b * DI + d) * 8 + p;
    ((float2*)chunkA)[idx] = make_float2(__expf(Sd * Av0), __expf(Sd * Av1));
    ((float2*)chunkB)[idx] = make_float2(h0, h1);
}

// ---------------------------------------------------------------------------
// Pass C: local scan seeded by an INLINE backward fold over the chunk-major
// composites (coalesced, early exit on underflow). (delta,u) packed; y bf16.
// ---------------------------------------------------------------------------
__global__ __launch_bounds__(256) void scan_chunkC(
    const unsigned int* __restrict__ du, const float* __restrict__ btct,
    const float* __restrict__ A_logs, const float* __restrict__ Ds,
    const float* __restrict__ chunkA, const float* __restrict__ chunkB,
    unsigned short* __restrict__ yt)
{
    const int c = blockIdx.x;
    const int g = blockIdx.y;
    const int b = blockIdx.z;
    const int t = threadIdx.x;
    const int grp = t >> 3, p = t & 7;
    const int d = g * 32 + grp;
    const float Av0 = -__expf(A_logs[d * NS + p]);
    const float Av1 = -__expf(A_logs[d * NS + p + 8]);
    const float Dv = Ds[d];
    const int j0 = c * LCHUNK;

    const unsigned int* dul = du + ((size_t)b * LL + j0) * DI + d;
    const float4*       bcl = (const float4*)btct + ((size_t)b * LL + j0) * 8 + p;
    unsigned short* yl = yt + ((size_t)b * LL + j0) * DI + d;

    const size_t off = ((size_t)b * DI + d) * 8 + p;
    const float2* A2 = (const float2*)chunkA;
    const float2* B2 = (const float2*)chunkB;
    float h0 = 0.f, h1 = 0.f, P0 = 1.f, P1 = 1.f;
    for (int i = c - 1; i >= 0; --i) {
        size_t ix = (size_t)i * CSTRIDE + off;
        float2 a = A2[ix], bv = B2[ix];
        h0 += P0 * bv.x;  h1 += P1 * bv.y;
        P0 *= a.x;        P1 *= a.y;
        if (fmaxf(fabsf(P0), fabsf(P1)) < 1e-30f) break;
    }

    unsigned int duv[4]; float4 bc[4];
    #pragma unroll
    for (int q = 0; q < 4; ++q) {
        duv[q] = dul[(size_t)q * DI]; bc[q] = bcl[(size_t)q * 8];
    }
    for (int j = 0; j < LCHUNK; j += 4) {
        unsigned int ndu[4]; float4 nbc[4];
        if (j + 4 < LCHUNK) {
            #pragma unroll
            for (int q = 0; q < 4; ++q) {
                int jj = j + 4 + q;
                ndu[q] = dul[(size_t)jj * DI]; nbc[q] = bcl[(size_t)jj * 8];
            }
        }
        #pragma unroll
        for (int q = 0; q < 4; ++q) {
            float dv = bf2f((unsigned short)(duv[q] & 0xffff));
            float uv = bf2f((unsigned short)(duv[q] >> 16));
            float e0 = __expf(dv * Av0);
            float e1 = __expf(dv * Av1);
            float duu = dv * uv;
            h0 = e0 * h0 + bc[q].x * duu;
            h1 = e1 * h1 + bc[q].y * duu;
            float acc = h0 * bc[q].z + h1 * bc[q].w;
            acc += __shfl_xor(acc, 4, 8);
            acc += __shfl_xor(acc, 2, 8);
            acc += __shfl_xor(acc, 1, 8);
            if (p == 0) yl[(size_t)(j + q) * DI] = f2bf(acc + uv * Dv);
        }
        #pragma unroll
        for (int q = 0; q < 4; ++q) { duv[q]=ndu[q]; bc[q]=nbc[q]; }
    }
}

// ---------------------------------------------------------------------------
// LayerNorm over d (384) + affine + z-mul (yt and z in bf16); unpermute
// folded into write; yn out in bf16.
// ---------------------------------------------------------------------------
__global__ __launch_bounds__(128) void ln_mul(
    const unsigned short* __restrict__ yt, const unsigned short* __restrict__ z,
    const int* __restrict__ scan_path,
    const float* __restrict__ ln_w, const float* __restrict__ ln_b,
    unsigned short* __restrict__ yn)
{
    const int j = blockIdx.x;
    const int b = blockIdx.y;
    const int l = scan_path[j];
    const int t = threadIdx.x;
    const unsigned short* row = yt + ((size_t)(b * LL + j)) * DI;
    float v0 = bf2f(row[t]), v1 = bf2f(row[t + 128]), v2 = bf2f(row[t + 256]);
    float s  = v0 + v1 + v2;
    float s2 = v0*v0 + v1*v1 + v2*v2;
    #pragma unroll
    for (int off = 32; off > 0; off >>= 1) {
        s  += __shfl_down(s, off);
        s2 += __shfl_down(s2, off);
    }
    __shared__ float red[4];
    if ((t & 63) == 0) { red[(t >> 6) * 2] = s; red[(t >> 6) * 2 + 1] = s2; }
    __syncthreads();
    float S  = red[0] + red[2];
    float S2 = red[1] + red[3];
    float mu  = S * (1.0f / DI);
    float var = S2 * (1.0f / DI) - mu * mu;
    float inv = rsqrtf(var + 1e-5f);

    const unsigned short* zr = z + ((size_t)(b * LL + l)) * DI;
    unsigned short* o = yn + ((size_t)(b * LL + l)) * DI;
    o[t]       = f2bf(((v0 - mu) * inv * ln_w[t]       + ln_b[t])       * bf2f(zr[t]));
    o[t + 128] = f2bf(((v1 - mu) * inv * ln_w[t + 128] + ln_b[t + 128]) * bf2f(zr[t + 128]));
    o[t + 256] = f2bf(((v2 - mu) * inv * ln_w[t + 256] + ln_b[t + 256]) * bf2f(zr[t + 256]));
}

// ---------------------------------------------------------------------------
extern "C" void kernel_launch(void* const* d_in, const int* in_sizes, int n_in,
                              void* d_out, int out_size, void* d_ws, size_t ws_size,
                              hipStream_t stream) {
    const float* x          = (const float*)d_in[0];
    const float* cond       = (const float*)d_in[1];
    const float* W_in       = (const float*)d_in[2];
    const float* W_con      = (const float*)d_in[3];
    const float* conv_w     = (const float*)d_in[4];
    const float* conv_b     = (const float*)d_in[5];
    const float* con_conv_w = (const float*)d_in[6];
    const float* con_conv_b = (const float*)d_in[7];
    const float* x_proj_w   = (const float*)d_in[8];
    const float* dt_proj_w  = (const float*)d_in[9];
    const float* dt_proj_b  = (const float*)d_in[10];
    const float* A_logs     = (const float*)d_in[11];
    const float* Ds         = (const float*)d_in[12];
    const float* ln_w       = (const float*)d_in[13];
    const float* ln_b       = (const float*)d_in[14];
    const float* W_out      = (const float*)d_in[15];
    const int*   scan_path  = (const int*)d_in[16];
    const int*   rev_path   = (const int*)d_in[17];

    float* ws = (float*)d_ws;
    const size_t S  = (size_t)BB * LL * DI;            // 3,145,728 floats
    const size_t SC = (size_t)NCHUNK * BB * DI * NS;   // 1,572,864 floats
    float* ytslab  = ws + 0 * S;                       // yt_bf (ushort, half used)
    float* zslab   = ws + 1 * S;                       // z_bf (ushort, half used)
    float* ynslab  = ws + 2 * S;                       // yn_bf (ushort, half used)
    float* duslab  = ws + 3 * S;                       // du (uint, full slab)
    float* btct    = ws + 4 * S;                       // BB*LL*32 floats, packed
    float* chunkA  = btct + (size_t)BB * LL * 32;
    float* chunkB  = chunkA + SC;
    float* bfpool  = chunkB + SC;                      // bf16 staging area

    unsigned short* yt_bf    = (unsigned short*)ytslab;            // ROWS*DI
    unsigned short* z_bf     = (unsigned short*)zslab;             // ROWS*DI
    unsigned short* yn_bf    = (unsigned short*)ynslab;            // ROWS*DI
    unsigned int*   du       = (unsigned int*)duslab;              // ROWS*DI uints
    unsigned short* s_bf     = (unsigned short*)bfpool;            // ROWS*DI
    unsigned short* xa_bf    = s_bf + (size_t)ROWS * DI;           // ROWS*DI
    unsigned short* c_bf     = xa_bf + (size_t)ROWS * DI;          // ROWS*DI
    unsigned short* w_in_bf  = c_bf + (size_t)ROWS * DI;           // 768*192
    unsigned short* w_con_bf = w_in_bf + 768 * DM;                 // 384*192
    unsigned short* w_out_bf = w_con_bf + 384 * DM;                // 192*384
    unsigned short* wcomb_bf = w_out_bf + 192 * DI;                // 448*384

    // 0) weight prep (casts + combined weight), one launch
    prep_weights<<<(73728 + NCOMB * DI + 255) / 256, 256, 0, stream>>>(
        W_in, W_con, W_out, x_proj_w, dt_proj_w,
        w_in_bf, w_con_bf, w_out_bf, wcomb_bf);

    // 1+2) dual GEMM: xz = x @ W_in.T (xa,z -> bf16) AND c = cond @ W_con.T (bf16)
    gemm_dual<<<dim3(ROWS / 64, 12, 2), 256, 0, stream>>>(
        x, cond, w_in_bf, w_con_bf, xa_bf, z_bf, c_bf);
    // 3) fused depthwise convs (bf16 in) + silu + scatter; u -> du high half
    dwconv2_scatter<<<dim3(64, 12, BB), 256, 0, stream>>>(
        xa_bf, c_bf, conv_w, conv_b, con_conv_w, con_conv_b,
        rev_path, (unsigned short*)du, s_bf);
    // 4) combined GEMM: delta (softplus -> du low half) + packed btct
    gemm_bf16<<<dim3(ROWS / 64, NCOMB / 64), 256, 0, stream>>>(
        s_bf, wcomb_bf, dt_proj_b, nullptr, (void*)btct,
        (unsigned short*)du, ROWS, NCOMB, DI, 2);
    // 5) chunked parallel scan: pass A, then pass C with coalesced inline fold
    scan_chunkA<<<dim3(NCHUNK, DI / 32, BB), 256, 0, stream>>>(
        du, btct, A_logs, chunkA, chunkB);
    scan_chunkC<<<dim3(NCHUNK, DI / 32, BB), 256, 0, stream>>>(
        du, btct, A_logs, Ds, chunkA, chunkB, yt_bf);
    // 6) LN + z-mul (unpermute folded in), yn in bf16
    ln_mul<<<dim3(LL, BB), 128, 0, stream>>>(yt_bf, z_bf, scan_path, ln_w, ln_b, yn_bf);
    // 7) out = yn @ W_out.T
    gemm_bf16<<<dim3(ROWS / 64, 192 / 64), 256, 0, stream>>>(
        yn_bf, w_out_bf, nullptr, (float*)d_out, nullptr, nullptr, ROWS, DM, DI, 1);
}